// Round 2
// baseline (1143.106 us; speedup 1.0000x reference)
//
#include <hip/hip_runtime.h>
#include <float.h>

// Problem constants (from setup_inputs)
#define NROWS 16384   // 8*2048
#define DDIM  768
#define KCODES 2048

// ---------------- Kernel A: ee[c] = sum_d emb[c][d]^2 ----------------
__global__ void ee_kernel(const float* __restrict__ emb, float* __restrict__ ee) {
    int c = blockIdx.x;
    const float* e = emb + (size_t)c * DDIM;
    int t = threadIdx.x; // 256 threads
    float s = 0.f;
    for (int i = t; i < DDIM; i += 256) { float v = e[i]; s += v * v; }
    for (int off = 32; off; off >>= 1) s += __shfl_down(s, off);
    __shared__ float red[4];
    if ((t & 63) == 0) red[t >> 6] = s;
    __syncthreads();
    if (t == 0) ee[c] = red[0] + red[1] + red[2] + red[3];
}

// ---------------- Kernel A2: zz[r] = sum_d z[r][d]^2 ----------------
// 1 wave per row; 4 rows per 256-thread block.
__global__ void zz_kernel(const float* __restrict__ z, float* __restrict__ zz) {
    const int t = threadIdx.x;
    const int row = blockIdx.x * 4 + (t >> 6);
    const int lane = t & 63;
    const float* zr = z + (size_t)row * DDIM;
    float s = 0.f;
    for (int i = lane; i < DDIM; i += 64) { float v = zr[i]; s += v * v; }
    for (int off = 32; off; off >>= 1) s += __shfl_down(s, off);
    if (lane == 0) zz[row] = s;
}

// ---------------- Kernel B: per-row argmin over codes ----------------
// Block: 32 rows x full K (looped in chunks of 128 codes). 256 threads.
// Thread tile: 2 rows x 8 codes.
// Comparator REPLICATES the reference's fp32 arithmetic exactly:
//   d = fl( fl(zz + ee[c]) - 2*dot )
// The ulp(768)=6.1e-5 quantization this induces is part of the reference's
// argmin semantics (near-ties collapse; first index wins) — we must match it.
#define BM 32
#define BN 128
#define BK 16
#define APAD 36    // A[BK][APAD]: worst 2-way bank aliasing (free)
#define BPAD 132
#define NCHUNK (KCODES / BN)   // 16
#define NKT    (DDIM / BK)     // 48

__global__ __launch_bounds__(256)
void argmin_kernel(const float* __restrict__ z, const float* __restrict__ emb,
                   const float* __restrict__ ee, const float* __restrict__ zz,
                   float* __restrict__ ids_f32) {
    __shared__ float A[BK][APAD];
    __shared__ float Bs[BK][BPAD];
    __shared__ float cval[BM][17];
    __shared__ int   cidx[BM][17];
    __shared__ float bval[BM];
    __shared__ int   bidx[BM];
    __shared__ float zzs[BM];

    const int t  = threadIdx.x;
    const int tx = t & 15;   // code group
    const int ty = t >> 4;   // 0..15 -> rows 2ty, 2ty+1
    const int row0 = blockIdx.x * BM;

    const int lk = t & 15;
    const int lr = t >> 4;   // 0..15

    if (t < BM) { bval[t] = FLT_MAX; bidx[t] = 0x7fffffff; zzs[t] = zz[row0 + t]; }
    __syncthreads();

    const float* zrow = z + (size_t)row0 * DDIM;

    for (int chunk = 0; chunk < NCHUNK; ++chunk) {
        const int c0 = chunk * BN;
        float acc[2][8];
        #pragma unroll
        for (int i = 0; i < 2; ++i)
            #pragma unroll
            for (int j = 0; j < 8; ++j) acc[i][j] = 0.f;

        // prefetch k-tile 0 into registers
        float ra0 = zrow[(size_t)lr * DDIM + lk];
        float ra1 = zrow[(size_t)(lr + 16) * DDIM + lk];
        float rb[8];
        #pragma unroll
        for (int j = 0; j < 8; ++j)
            rb[j] = emb[(size_t)(c0 + lr + 16 * j) * DDIM + lk];

        for (int kt = 0; kt < NKT; ++kt) {
            __syncthreads();
            A[lk][lr]      = ra0;
            A[lk][lr + 16] = ra1;
            #pragma unroll
            for (int j = 0; j < 8; ++j) Bs[lk][lr + 16 * j] = rb[j];
            __syncthreads();

            if (kt + 1 < NKT) {
                const int k1 = (kt + 1) * BK + lk;
                ra0 = zrow[(size_t)lr * DDIM + k1];
                ra1 = zrow[(size_t)(lr + 16) * DDIM + k1];
                #pragma unroll
                for (int j = 0; j < 8; ++j)
                    rb[j] = emb[(size_t)(c0 + lr + 16 * j) * DDIM + k1];
            }

            #pragma unroll
            for (int kk = 0; kk < BK; ++kk) {
                const float2 a2 = *(const float2*)&A[kk][2 * ty];
                const float4 p  = *(const float4*)&Bs[kk][4 * tx];
                const float4 q  = *(const float4*)&Bs[kk][64 + 4 * tx];
                const float bb[8] = {p.x, p.y, p.z, p.w, q.x, q.y, q.z, q.w};
                #pragma unroll
                for (int j = 0; j < 8; ++j) {
                    acc[0][j] += a2.x * bb[j];
                    acc[1][j] += a2.y * bb[j];
                }
            }
        }

        // epilogue: faithful fp32 distance, per-thread candidate, cross-tx reduce
        const float4 eA = *(const float4*)&ee[c0 + 4 * tx];
        const float4 eB = *(const float4*)&ee[c0 + 64 + 4 * tx];
        const float eev[8] = {eA.x, eA.y, eA.z, eA.w, eB.x, eB.y, eB.z, eB.w};
        #pragma unroll
        for (int i = 0; i < 2; ++i) {
            const float zzr = zzs[2 * ty + i];
            float bv = FLT_MAX; int bi = 0x7fffffff;
            #pragma unroll
            for (int j = 0; j < 8; ++j) {
                const int code = (j < 4) ? (c0 + 4 * tx + j) : (c0 + 64 + 4 * tx + (j - 4));
                const float t1 = zzr + eev[j];          // fp32 round (reference order)
                const float d  = t1 - 2.0f * acc[i][j]; // 2*acc exact; fp32 round
                if (d < bv || (d == bv && code < bi)) { bv = d; bi = code; }
            }
            cval[2 * ty + i][tx] = bv;
            cidx[2 * ty + i][tx] = bi;
        }
        __syncthreads();
        if (t < BM) {
            float bv = bval[t]; int bi = bidx[t];
            #pragma unroll
            for (int x = 0; x < 16; ++x) {
                const float v = cval[t][x]; const int id = cidx[t][x];
                if (v < bv || (v == bv && id < bi)) { bv = v; bi = id; }
            }
            bval[t] = bv; bidx[t] = bi;
        }
    }

    if (t < BM) ids_f32[row0 + t] = (float)bidx[t];  // ids exact in fp32 (<2^11)
}

// ---------------- Kernel C: gather + straight-through + loss partials ----------------
__global__ void gather_kernel(const float* __restrict__ z, const float* __restrict__ emb,
                              const float* __restrict__ ids_f32, float* __restrict__ out0,
                              float* __restrict__ part) {
    const int b = blockIdx.x;       // 1024
    const int t = threadIdx.x;
    const size_t base = (size_t)b * 16 * DDIM;
    float s = 0.f;
    for (int l = 0; l < 48; ++l) {
        const int off = l * 256 + t;
        const int rloc = off / DDIM;
        const int d = off - rloc * DDIM;
        const int id = (int)ids_f32[b * 16 + rloc];
        const float zv = z[base + off];
        const float ev = emb[(size_t)id * DDIM + d];
        out0[base + off] = zv + (ev - zv);   // straight-through value, faithful order
        const float diff = zv - ev;
        s += diff * diff;
    }
    for (int off = 32; off; off >>= 1) s += __shfl_down(s, off);
    __shared__ float red[4];
    if ((t & 63) == 0) red[t >> 6] = s;
    __syncthreads();
    if (t == 0) part[b] = red[0] + red[1] + red[2] + red[3];
}

// ---------------- Kernel D: final loss reduction (fp64 accumulate) ----------------
__global__ void loss_kernel(const float* __restrict__ part, float* __restrict__ out_loss) {
    const int t = threadIdx.x; // 256
    double s = 0.0;
    for (int i = t; i < 1024; i += 256) s += (double)part[i];
    for (int off = 32; off; off >>= 1) s += __shfl_down(s, off);
    __shared__ double red[4];
    if ((t & 63) == 0) red[t >> 6] = s;
    __syncthreads();
    if (t == 0) {
        const double total = red[0] + red[1] + red[2] + red[3];
        out_loss[0] = (float)(0.25 * (total / (double)((size_t)NROWS * DDIM)));
    }
}

extern "C" void kernel_launch(void* const* d_in, const int* in_sizes, int n_in,
                              void* d_out, int out_size, void* d_ws, size_t ws_size,
                              hipStream_t stream) {
    const float* z   = (const float*)d_in[0];
    const float* emb = (const float*)d_in[1];

    float* out0     = (float*)d_out;                       // z_q_st [16384*768]
    float* out_ids  = out0 + (size_t)NROWS * DDIM;         // ids    [16384]
    float* out_loss = out_ids + NROWS;                     // loss   [1]

    float* ee   = (float*)d_ws;                            // 2048 f32
    float* part = (float*)((char*)d_ws + 8192);            // 1024 f32
    float* zzws = (float*)((char*)d_ws + 16384);           // 16384 f32

    ee_kernel<<<KCODES, 256, 0, stream>>>(emb, ee);
    zz_kernel<<<NROWS / 4, 256, 0, stream>>>(z, zzws);
    argmin_kernel<<<NROWS / BM, 256, 0, stream>>>(z, emb, ee, zzws, out_ids);
    gather_kernel<<<NROWS / 16, 256, 0, stream>>>(z, emb, out_ids, out0, part);
    loss_kernel<<<1, 256, 0, stream>>>(part, out_loss);
}

// Round 3
// 978.144 us; speedup vs baseline: 1.1686x; 1.1686x over previous
//
#include <hip/hip_runtime.h>
#include <float.h>

// Problem constants (from setup_inputs)
#define NROWS 16384   // 8*2048
#define DDIM  768
#define KCODES 2048

// ---------------- Kernel A: ee[c] = sum_d emb[c][d]^2 ----------------
// UNCHANGED from passing round (comparator inputs must stay bitwise identical).
__global__ void ee_kernel(const float* __restrict__ emb, float* __restrict__ ee) {
    int c = blockIdx.x;
    const float* e = emb + (size_t)c * DDIM;
    int t = threadIdx.x; // 256 threads
    float s = 0.f;
    for (int i = t; i < DDIM; i += 256) { float v = e[i]; s += v * v; }
    for (int off = 32; off; off >>= 1) s += __shfl_down(s, off);
    __shared__ float red[4];
    if ((t & 63) == 0) red[t >> 6] = s;
    __syncthreads();
    if (t == 0) ee[c] = red[0] + red[1] + red[2] + red[3];
}

// ---------------- Kernel A2: zz[r] = sum_d z[r][d]^2 (UNCHANGED) ------
__global__ void zz_kernel(const float* __restrict__ z, float* __restrict__ zz) {
    const int t = threadIdx.x;
    const int row = blockIdx.x * 4 + (t >> 6);
    const int lane = t & 63;
    const float* zr = z + (size_t)row * DDIM;
    float s = 0.f;
    for (int i = lane; i < DDIM; i += 64) { float v = zr[i]; s += v * v; }
    for (int off = 32; off; off >>= 1) s += __shfl_down(s, off);
    if (lane == 0) zz[row] = s;
}

// ---------------- Kernel B: per-row argmin over codes ----------------
// BM=32 rows, codes split across SPLITC=2 blocks (1024 codes each, chunks of
// BN=128). 256 threads, 4x4 register tile. BK=32 staging via float4 global
// loads + transpose scatter to LDS. Per-(row,code) fp32 FMA chain keeps
// strict sequential k-order 0..767 -> accumulators BITWISE IDENTICAL to the
// passing round. Comparator d = fl(fl(zz+ee)-2*acc) identical. Lexicographic
// (d, code) min is order-independent -> tie-break identical.
#define BM 32
#define BN 128
#define BKS 32
#define SPLITC 2
#define CODES_PER_BLOCK (KCODES / SPLITC)  // 1024
#define NCHUNK (CODES_PER_BLOCK / BN)      // 8
#define NSTAGE (DDIM / BKS)                // 24
#define APADR 33
#define BPADC 132                          // 132*4 = 528 = 16*33 -> float4-aligned rows

__global__ __launch_bounds__(256)
void argmin_kernel(const float* __restrict__ z, const float* __restrict__ emb,
                   const float* __restrict__ ee, const float* __restrict__ zz,
                   float* __restrict__ pval, int* __restrict__ pidx) {
    __shared__ float Af[BKS][APADR];
    __shared__ float Bf[BKS][BPADC];
    __shared__ float cval[BM][33];
    __shared__ int   cidx[BM][33];
    __shared__ float zzs[BM];

    const int t    = threadIdx.x;
    const int part = blockIdx.x & (SPLITC - 1);
    const int rb   = blockIdx.x >> 1;
    const int row0 = rb * BM;
    const int cbase = part * CODES_PER_BLOCK;

    const int tx = t & 31;    // code group: 4 codes at 4*tx
    const int ty = t >> 5;    // row group: 4 rows at 4*ty
    const int sr = t >> 3;    // staging row (A) / code (B), 0..31
    const int sk = 4 * (t & 7); // staging k offset 0,4,...,28

    if (t < BM) zzs[t] = zz[row0 + t];

    float bv[4]; int bi[4];
    #pragma unroll
    for (int i = 0; i < 4; ++i) { bv[i] = FLT_MAX; bi[i] = 0x7fffffff; }

    const float* zt = z + (size_t)(row0 + sr) * DDIM;

    for (int chunk = 0; chunk < NCHUNK; ++chunk) {
        const int c0 = cbase + chunk * BN;
        const float* ebase = emb + (size_t)(c0 + sr) * DDIM;

        float acc[4][4];
        #pragma unroll
        for (int i = 0; i < 4; ++i)
            #pragma unroll
            for (int j = 0; j < 4; ++j) acc[i][j] = 0.f;

        // prefetch stage 0
        float4 pa = *(const float4*)&zt[sk];
        float4 pb[4];
        #pragma unroll
        for (int m = 0; m < 4; ++m)
            pb[m] = *(const float4*)&ebase[(size_t)(32 * m) * DDIM + sk];

        for (int s = 0; s < NSTAGE; ++s) {
            __syncthreads();
            Af[sk + 0][sr] = pa.x; Af[sk + 1][sr] = pa.y;
            Af[sk + 2][sr] = pa.z; Af[sk + 3][sr] = pa.w;
            #pragma unroll
            for (int m = 0; m < 4; ++m) {
                Bf[sk + 0][sr + 32 * m] = pb[m].x;
                Bf[sk + 1][sr + 32 * m] = pb[m].y;
                Bf[sk + 2][sr + 32 * m] = pb[m].z;
                Bf[sk + 3][sr + 32 * m] = pb[m].w;
            }
            __syncthreads();

            if (s + 1 < NSTAGE) {
                const int k1 = (s + 1) * BKS + sk;
                pa = *(const float4*)&zt[k1];
                #pragma unroll
                for (int m = 0; m < 4; ++m)
                    pb[m] = *(const float4*)&ebase[(size_t)(32 * m) * DDIM + k1];
            }

            #pragma unroll
            for (int kk = 0; kk < BKS; ++kk) {
                const float4 a4 = *(const float4*)&Af[kk][4 * ty];
                const float4 b4 = *(const float4*)&Bf[kk][4 * tx];
                const float aa[4] = {a4.x, a4.y, a4.z, a4.w};
                const float bb[4] = {b4.x, b4.y, b4.z, b4.w};
                #pragma unroll
                for (int i = 0; i < 4; ++i)
                    #pragma unroll
                    for (int j = 0; j < 4; ++j)
                        acc[i][j] += aa[i] * bb[j];
            }
        }

        // epilogue: faithful fp32 distance, running per-thread lexmin
        const float4 e4 = *(const float4*)&ee[c0 + 4 * tx];
        const float eev[4] = {e4.x, e4.y, e4.z, e4.w};
        #pragma unroll
        for (int i = 0; i < 4; ++i) {
            const float zzr = zzs[4 * ty + i];
            #pragma unroll
            for (int j = 0; j < 4; ++j) {
                const int code = c0 + 4 * tx + j;
                const float t1 = zzr + eev[j];          // fp32 round (ref order)
                const float d  = t1 - 2.0f * acc[i][j]; // 2*acc exact; fp32 round
                if (d < bv[i] || (d == bv[i] && code < bi[i])) { bv[i] = d; bi[i] = code; }
            }
        }
    }

    // cross-thread reduce per row (over 32 tx groups)
    __syncthreads();
    #pragma unroll
    for (int i = 0; i < 4; ++i) { cval[4 * ty + i][tx] = bv[i]; cidx[4 * ty + i][tx] = bi[i]; }
    __syncthreads();
    if (t < BM) {
        float v = FLT_MAX; int id = 0x7fffffff;
        #pragma unroll
        for (int x = 0; x < 32; ++x) {
            const float cv = cval[t][x]; const int ci = cidx[t][x];
            if (cv < v || (cv == v && ci < id)) { v = cv; id = ci; }
        }
        pval[part * NROWS + row0 + t] = v;
        pidx[part * NROWS + row0 + t] = id;
    }
}

// ---------------- Kernel B2: combine the SPLITC partials ----------------
__global__ void combine_kernel(const float* __restrict__ pval, const int* __restrict__ pidx,
                               float* __restrict__ ids_f32) {
    const int r = blockIdx.x * 256 + threadIdx.x;
    float v = pval[r];           int id = pidx[r];
    const float v1 = pval[NROWS + r]; const int i1 = pidx[NROWS + r];
    if (v1 < v || (v1 == v && i1 < id)) { v = v1; id = i1; }
    ids_f32[r] = (float)id;      // exact in fp32 (<2^11)
}

// ---------------- Kernel C: gather + straight-through + loss (UNCHANGED) ---
__global__ void gather_kernel(const float* __restrict__ z, const float* __restrict__ emb,
                              const float* __restrict__ ids_f32, float* __restrict__ out0,
                              float* __restrict__ part) {
    const int b = blockIdx.x;       // 1024
    const int t = threadIdx.x;
    const size_t base = (size_t)b * 16 * DDIM;
    float s = 0.f;
    for (int l = 0; l < 48; ++l) {
        const int off = l * 256 + t;
        const int rloc = off / DDIM;
        const int d = off - rloc * DDIM;
        const int id = (int)ids_f32[b * 16 + rloc];
        const float zv = z[base + off];
        const float ev = emb[(size_t)id * DDIM + d];
        out0[base + off] = zv + (ev - zv);
        const float diff = zv - ev;
        s += diff * diff;
    }
    for (int off = 32; off; off >>= 1) s += __shfl_down(s, off);
    __shared__ float red[4];
    if ((t & 63) == 0) red[t >> 6] = s;
    __syncthreads();
    if (t == 0) part[b] = red[0] + red[1] + red[2] + red[3];
}

// ---------------- Kernel D: final loss reduction (UNCHANGED) ----------------
__global__ void loss_kernel(const float* __restrict__ part, float* __restrict__ out_loss) {
    const int t = threadIdx.x; // 256
    double s = 0.0;
    for (int i = t; i < 1024; i += 256) s += (double)part[i];
    for (int off = 32; off; off >>= 1) s += __shfl_down(s, off);
    __shared__ double red[4];
    if ((t & 63) == 0) red[t >> 6] = s;
    __syncthreads();
    if (t == 0) {
        const double total = red[0] + red[1] + red[2] + red[3];
        out_loss[0] = (float)(0.25 * (total / (double)((size_t)NROWS * DDIM)));
    }
}

extern "C" void kernel_launch(void* const* d_in, const int* in_sizes, int n_in,
                              void* d_out, int out_size, void* d_ws, size_t ws_size,
                              hipStream_t stream) {
    const float* z   = (const float*)d_in[0];
    const float* emb = (const float*)d_in[1];

    float* out0     = (float*)d_out;                       // z_q_st [16384*768]
    float* out_ids  = out0 + (size_t)NROWS * DDIM;         // ids    [16384]
    float* out_loss = out_ids + NROWS;                     // loss   [1]

    float* ee   = (float*)d_ws;                            // 2048 f32
    float* part = (float*)((char*)d_ws + 8192);            // 1024 f32
    float* zzws = (float*)((char*)d_ws + 16384);           // 16384 f32
    float* pval = (float*)((char*)d_ws + 81920);           // 2*16384 f32
    int*   pidx = (int*)  ((char*)d_ws + 81920 + 131072);  // 2*16384 i32

    ee_kernel<<<KCODES, 256, 0, stream>>>(emb, ee);
    zz_kernel<<<NROWS / 4, 256, 0, stream>>>(z, zzws);
    argmin_kernel<<<(NROWS / BM) * SPLITC, 256, 0, stream>>>(z, emb, ee, zzws, pval, pidx);
    combine_kernel<<<NROWS / 256, 256, 0, stream>>>(pval, pidx, out_ids);
    gather_kernel<<<NROWS / 16, 256, 0, stream>>>(z, emb, out_ids, out0, part);
    loss_kernel<<<1, 256, 0, stream>>>(part, out_loss);
}

// Round 4
// 325.516 us; speedup vs baseline: 3.5117x; 3.0049x over previous
//
#include <hip/hip_runtime.h>
#include <float.h>

typedef unsigned short ushort_t;
typedef unsigned int uint_t;

// Problem constants
#define NROWS 16384   // 8*2048
#define DDIM  768
#define KCODES 2048
#define KP    1536    // packed split K' = 2*768

// bf16 helpers (RNE), used consistently everywhere
__device__ __forceinline__ ushort_t f2bf(float x) {
    uint_t u = __float_as_uint(x);
    uint_t r = (u + 0x7fffu + ((u >> 16) & 1u)) >> 16;
    return (ushort_t)r;
}
__device__ __forceinline__ float bf2f(ushort_t h) {
    return __uint_as_float(((uint_t)h) << 16);
}

// ---------------- ee[c] = sum_d emb[c][d]^2 (UNCHANGED, comparator input) --
__global__ void ee_kernel(const float* __restrict__ emb, float* __restrict__ ee) {
    int c = blockIdx.x;
    const float* e = emb + (size_t)c * DDIM;
    int t = threadIdx.x;
    float s = 0.f;
    for (int i = t; i < DDIM; i += 256) { float v = e[i]; s += v * v; }
    for (int off = 32; off; off >>= 1) s += __shfl_down(s, off);
    __shared__ float red[4];
    if ((t & 63) == 0) red[t >> 6] = s;
    __syncthreads();
    if (t == 0) ee[c] = red[0] + red[1] + red[2] + red[3];
}

// ---------------- zz[r] = sum_d z[r][d]^2 (UNCHANGED) ----------------------
__global__ void zz_kernel(const float* __restrict__ z, float* __restrict__ zz) {
    const int t = threadIdx.x;
    const int row = blockIdx.x * 4 + (t >> 6);
    const int lane = t & 63;
    const float* zr = z + (size_t)row * DDIM;
    float s = 0.f;
    for (int i = lane; i < DDIM; i += 64) { float v = zr[i]; s += v * v; }
    for (int off = 32; off; off >>= 1) s += __shfl_down(s, off);
    if (lane == 0) zz[row] = s;
}

// ---------------- split: x -> (hi=bf16(x), mid=bf16(x-hi)) packed rows -----
// dst row layout: [hi 0..767 | mid 0..767] (K'=1536 bf16 per row)
__global__ void split_kernel(const float* __restrict__ src, ushort_t* __restrict__ dst) {
    const int i = blockIdx.x * 256 + threadIdx.x;   // float4 index
    const float4 v = ((const float4*)src)[i];
    const int row = i / 192;                        // 192 float4 per row
    const int k   = (i - row * 192) * 4;
    ushort4 h, m;
    float x;
    x = v.x; h.x = f2bf(x); m.x = f2bf(x - bf2f(h.x));
    x = v.y; h.y = f2bf(x); m.y = f2bf(x - bf2f(h.y));
    x = v.z; h.z = f2bf(x); m.z = f2bf(x - bf2f(h.z));
    x = v.w; h.w = f2bf(x); m.w = f2bf(x - bf2f(h.w));
    *(ushort4*)(dst + (size_t)row * KP + k)       = h;
    *(ushort4*)(dst + (size_t)row * KP + 768 + k) = m;
}

// ---------------- Phase 1: bf16 MFMA GEMM, d~ = ee - 2*dot~  ---------------
// m97 structure: 128x128 tile, BK=32, 16x16x32 bf16 MFMA, global_load_lds(16B),
// XOR chunk swizzle keeps frag ds_read_b128 at 2-way banking (free).
typedef __attribute__((ext_vector_type(8))) short bf16x8;
typedef __attribute__((ext_vector_type(4))) float f32x4;

__device__ __forceinline__ int swz(int r) { return (r & 3) ^ ((r >> 2) & 3); }

__global__ __launch_bounds__(256)
void mfma_kernel(const ushort_t* __restrict__ Ab, const ushort_t* __restrict__ Bb,
                 const float* __restrict__ ee, ushort_t* __restrict__ dtil) {
    __shared__ ushort_t Als[128 * 32];
    __shared__ ushort_t Bls[128 * 32];
    const int t = threadIdx.x;
    const int w = t >> 6, l = t & 63;
    const int bx = blockIdx.x & 127, by = blockIdx.x >> 7;
    const int row0 = bx << 7, col0 = by << 7;

    f32x4 acc[4][4];
    #pragma unroll
    for (int i = 0; i < 4; ++i)
        #pragma unroll
        for (int j = 0; j < 4; ++j) acc[i][j] = (f32x4){0.f, 0.f, 0.f, 0.f};

    const int sri  = l >> 2;       // staging row within 16-row wave load
    const int slot = l & 3;        // physical 16B slot within 64B row
    const int rha = (w & 1) << 6;  // A row half
    const int rhb = (w >> 1) << 6; // B row half (codes)

    for (int kt = 0; kt < 48; ++kt) {
        const int kb = kt << 5;    // bf16 k offset within K'=1536
        __syncthreads();           // previous tile's ds_reads done
        #pragma unroll
        for (int q = 0; q < 2; ++q) {
            const int r0 = ((w << 1) + q) << 4;    // 0,16,...,112 across waves
            const int ra = r0 + sri;
            const int c  = slot ^ swz(ra);         // logical chunk for this slot
            const ushort_t* gpa = Ab + (size_t)(row0 + ra) * KP + kb + (c << 3);
            __builtin_amdgcn_global_load_lds(
                (const __attribute__((address_space(1))) void*)gpa,
                (__attribute__((address_space(3))) void*)((char*)Als + (r0 << 6)), 16, 0, 0);
            const ushort_t* gpb = Bb + (size_t)(col0 + ra) * KP + kb + (c << 3);
            __builtin_amdgcn_global_load_lds(
                (const __attribute__((address_space(1))) void*)gpb,
                (__attribute__((address_space(3))) void*)((char*)Bls + (r0 << 6)), 16, 0, 0);
        }
        __syncthreads();           // vmcnt(0) drained by compiler before barrier

        bf16x8 af[4], bfr[4];
        #pragma unroll
        for (int mi = 0; mi < 4; ++mi) {
            const int r = rha + (mi << 4) + (l & 15);
            const int s = (l >> 4) ^ swz(r);
            af[mi] = *(const bf16x8*)&Als[(r << 5) + (s << 3)];
        }
        #pragma unroll
        for (int ni = 0; ni < 4; ++ni) {
            const int r = rhb + (ni << 4) + (l & 15);
            const int s = (l >> 4) ^ swz(r);
            bfr[ni] = *(const bf16x8*)&Bls[(r << 5) + (s << 3)];
        }
        #pragma unroll
        for (int mi = 0; mi < 4; ++mi)
            #pragma unroll
            for (int ni = 0; ni < 4; ++ni)
                acc[mi][ni] = __builtin_amdgcn_mfma_f32_16x16x32_bf16(
                    af[mi], bfr[ni], acc[mi][ni], 0, 0, 0);
    }

    // epilogue: d~ = ee - 2*dot~, bf16 store. C/D map: row=(l>>4)*4+r, col=l&15.
    #pragma unroll
    for (int ni = 0; ni < 4; ++ni) {
        const int n = rhb + (ni << 4) + (l & 15);
        const float ec = ee[col0 + n];
        #pragma unroll
        for (int mi = 0; mi < 4; ++mi) {
            #pragma unroll
            for (int r = 0; r < 4; ++r) {
                const int m = rha + (mi << 4) + ((l >> 4) << 2) + r;
                dtil[(size_t)(row0 + m) * KCODES + col0 + n] = f2bf(ec - 2.0f * acc[mi][ni][r]);
            }
        }
    }
}

// ---------------- Phase 2: candidate select + EXACT fp32 re-check ----------
// Margin proof: ref winner satisfies D(c*) <= D(cmin) + 2*6.2e-5 (fp32-grid tie),
// bf16 store adds <=1.3e-4 each side, split deviation <=1e-6
// => d~(c*) <= min(d~) + 3.9e-4 < margin 6e-4.
__global__ __launch_bounds__(256)
void select_kernel(const ushort_t* __restrict__ dtil, const float* __restrict__ ee,
                   const float* __restrict__ zz, const float* __restrict__ z,
                   const float* __restrict__ emb, float* __restrict__ ids_f32) {
    const int row = blockIdx.x;
    const int t = threadIdx.x;
    const ushort_t* drow = dtil + (size_t)row * KCODES;

    float dv[8];
    {
        ushort4 u0 = ((const ushort4*)drow)[2 * t];
        ushort4 u1 = ((const ushort4*)drow)[2 * t + 1];
        dv[0] = bf2f(u0.x); dv[1] = bf2f(u0.y); dv[2] = bf2f(u0.z); dv[3] = bf2f(u0.w);
        dv[4] = bf2f(u1.x); dv[5] = bf2f(u1.y); dv[6] = bf2f(u1.z); dv[7] = bf2f(u1.w);
    }
    __shared__ float sred[256];
    float lm = dv[0];
    #pragma unroll
    for (int j = 1; j < 8; ++j) lm = fminf(lm, dv[j]);
    sred[t] = lm;
    __syncthreads();
    for (int s = 128; s; s >>= 1) { if (t < s) sred[t] = fminf(sred[t], sred[t + s]); __syncthreads(); }
    const float T = sred[0] + 6e-4f;
    __syncthreads();

    __shared__ int cnt;
    __shared__ int cand[64];
    __shared__ float bsv;
    __shared__ int bsi;
    if (t == 0) { cnt = 0; bsv = FLT_MAX; bsi = 0x7fffffff; }
    __syncthreads();
    #pragma unroll
    for (int j = 0; j < 8; ++j) {
        if (dv[j] <= T) {
            int p = atomicAdd(&cnt, 1);
            if (p < 64) cand[p] = 8 * t + j;
        }
    }
    __syncthreads();
    const int n = cnt < 64 ? cnt : 64;

    const float zzr = zz[row];
    const float* zr = z + (size_t)row * DDIM;
    for (int i = 0; i < n; ++i) {
        const int c = cand[i];
        const float* er = emb + (size_t)c * DDIM;
        float p = 0.f;
        for (int k = t; k < DDIM; k += 256) p += zr[k] * er[k];
        sred[t] = p;
        __syncthreads();
        for (int s = 128; s; s >>= 1) { if (t < s) sred[t] += sred[t + s]; __syncthreads(); }
        if (t == 0) {
            const float dot = sred[0];
            const float t1 = zzr + ee[c];       // fp32 round (ref order)
            const float d  = t1 - 2.0f * dot;   // fp32 round
            if (d < bsv || (d == bsv && c < bsi)) { bsv = d; bsi = c; }
        }
        __syncthreads();
    }
    if (t == 0) ids_f32[row] = (float)bsi;
}

// ---------------- gather + straight-through + loss partials (UNCHANGED) ----
__global__ void gather_kernel(const float* __restrict__ z, const float* __restrict__ emb,
                              const float* __restrict__ ids_f32, float* __restrict__ out0,
                              float* __restrict__ part) {
    const int b = blockIdx.x;
    const int t = threadIdx.x;
    const size_t base = (size_t)b * 16 * DDIM;
    float s = 0.f;
    for (int l = 0; l < 48; ++l) {
        const int off = l * 256 + t;
        const int rloc = off / DDIM;
        const int d = off - rloc * DDIM;
        const int id = (int)ids_f32[b * 16 + rloc];
        const float zv = z[base + off];
        const float ev = emb[(size_t)id * DDIM + d];
        out0[base + off] = zv + (ev - zv);
        const float diff = zv - ev;
        s += diff * diff;
    }
    for (int off = 32; off; off >>= 1) s += __shfl_down(s, off);
    __shared__ float red[4];
    if ((t & 63) == 0) red[t >> 6] = s;
    __syncthreads();
    if (t == 0) part[b] = red[0] + red[1] + red[2] + red[3];
}

__global__ void loss_kernel(const float* __restrict__ part, float* __restrict__ out_loss) {
    const int t = threadIdx.x;
    double s = 0.0;
    for (int i = t; i < 1024; i += 256) s += (double)part[i];
    for (int off = 32; off; off >>= 1) s += __shfl_down(s, off);
    __shared__ double red[4];
    if ((t & 63) == 0) red[t >> 6] = s;
    __syncthreads();
    if (t == 0) {
        const double total = red[0] + red[1] + red[2] + red[3];
        out_loss[0] = (float)(0.25 * (total / (double)((size_t)NROWS * DDIM)));
    }
}

// ================= Fallback (round-3 exact fp32 path, proven) ==============
#define BM 32
#define BN 128
#define BKS 32
#define SPLITC 2
#define CODES_PER_BLOCK (KCODES / SPLITC)
#define NCHUNK (CODES_PER_BLOCK / BN)
#define NSTAGE (DDIM / BKS)
#define APADR 33
#define BPADC 132

__global__ __launch_bounds__(256)
void argmin_kernel(const float* __restrict__ z, const float* __restrict__ emb,
                   const float* __restrict__ ee, const float* __restrict__ zz,
                   float* __restrict__ pval, int* __restrict__ pidx) {
    __shared__ float Af[BKS][APADR];
    __shared__ float Bf[BKS][BPADC];
    __shared__ float cval[BM][33];
    __shared__ int   cidx[BM][33];
    __shared__ float zzs[BM];
    const int t = threadIdx.x;
    const int part = blockIdx.x & (SPLITC - 1);
    const int rb = blockIdx.x >> 1;
    const int row0 = rb * BM;
    const int cbase = part * CODES_PER_BLOCK;
    const int tx = t & 31, ty = t >> 5;
    const int sr = t >> 3;
    const int sk = 4 * (t & 7);
    if (t < BM) zzs[t] = zz[row0 + t];
    float bv[4]; int bi[4];
    #pragma unroll
    for (int i = 0; i < 4; ++i) { bv[i] = FLT_MAX; bi[i] = 0x7fffffff; }
    const float* zt = z + (size_t)(row0 + sr) * DDIM;
    for (int chunk = 0; chunk < NCHUNK; ++chunk) {
        const int c0 = cbase + chunk * BN;
        const float* ebase = emb + (size_t)(c0 + sr) * DDIM;
        float acc[4][4];
        #pragma unroll
        for (int i = 0; i < 4; ++i)
            #pragma unroll
            for (int j = 0; j < 4; ++j) acc[i][j] = 0.f;
        float4 pa = *(const float4*)&zt[sk];
        float4 pb[4];
        #pragma unroll
        for (int m = 0; m < 4; ++m) pb[m] = *(const float4*)&ebase[(size_t)(32 * m) * DDIM + sk];
        for (int s = 0; s < NSTAGE; ++s) {
            __syncthreads();
            Af[sk + 0][sr] = pa.x; Af[sk + 1][sr] = pa.y;
            Af[sk + 2][sr] = pa.z; Af[sk + 3][sr] = pa.w;
            #pragma unroll
            for (int m = 0; m < 4; ++m) {
                Bf[sk + 0][sr + 32 * m] = pb[m].x;
                Bf[sk + 1][sr + 32 * m] = pb[m].y;
                Bf[sk + 2][sr + 32 * m] = pb[m].z;
                Bf[sk + 3][sr + 32 * m] = pb[m].w;
            }
            __syncthreads();
            if (s + 1 < NSTAGE) {
                const int k1 = (s + 1) * BKS + sk;
                pa = *(const float4*)&zt[k1];
                #pragma unroll
                for (int m = 0; m < 4; ++m)
                    pb[m] = *(const float4*)&ebase[(size_t)(32 * m) * DDIM + k1];
            }
            #pragma unroll
            for (int kk = 0; kk < BKS; ++kk) {
                const float4 a4 = *(const float4*)&Af[kk][4 * ty];
                const float4 b4 = *(const float4*)&Bf[kk][4 * tx];
                const float aa[4] = {a4.x, a4.y, a4.z, a4.w};
                const float bb[4] = {b4.x, b4.y, b4.z, b4.w};
                #pragma unroll
                for (int i = 0; i < 4; ++i)
                    #pragma unroll
                    for (int j = 0; j < 4; ++j) acc[i][j] += aa[i] * bb[j];
            }
        }
        const float4 e4 = *(const float4*)&ee[c0 + 4 * tx];
        const float eev[4] = {e4.x, e4.y, e4.z, e4.w};
        #pragma unroll
        for (int i = 0; i < 4; ++i) {
            const float zzr = zzs[4 * ty + i];
            #pragma unroll
            for (int j = 0; j < 4; ++j) {
                const int code = c0 + 4 * tx + j;
                const float t1 = zzr + eev[j];
                const float d  = t1 - 2.0f * acc[i][j];
                if (d < bv[i] || (d == bv[i] && code < bi[i])) { bv[i] = d; bi[i] = code; }
            }
        }
    }
    __syncthreads();
    #pragma unroll
    for (int i = 0; i < 4; ++i) { cval[4 * ty + i][tx] = bv[i]; cidx[4 * ty + i][tx] = bi[i]; }
    __syncthreads();
    if (t < BM) {
        float v = FLT_MAX; int id = 0x7fffffff;
        #pragma unroll
        for (int x = 0; x < 32; ++x) {
            const float cv = cval[t][x]; const int ci = cidx[t][x];
            if (cv < v || (cv == v && ci < id)) { v = cv; id = ci; }
        }
        pval[part * NROWS + row0 + t] = v;
        pidx[part * NROWS + row0 + t] = id;
    }
}

__global__ void combine_kernel(const float* __restrict__ pval, const int* __restrict__ pidx,
                               float* __restrict__ ids_f32) {
    const int r = blockIdx.x * 256 + threadIdx.x;
    float v = pval[r];           int id = pidx[r];
    const float v1 = pval[NROWS + r]; const int i1 = pidx[NROWS + r];
    if (v1 < v || (v1 == v && i1 < id)) { v = v1; id = i1; }
    ids_f32[r] = (float)id;
}

// ================= launch ==================================================
#define EE_OFF   0
#define ZZ_OFF   8192
#define PART_OFF 73728
#define PV_OFF   81920
#define AB_OFF   344064
#define BB_OFF   (AB_OFF + (size_t)NROWS * KP * 2)             // +50331648
#define DT_OFF   (BB_OFF + (size_t)KCODES * KP * 2)            // +6291456
#define WS_NEED  (DT_OFF + (size_t)NROWS * KCODES * 2)         // ~118.3 MB

extern "C" void kernel_launch(void* const* d_in, const int* in_sizes, int n_in,
                              void* d_out, int out_size, void* d_ws, size_t ws_size,
                              hipStream_t stream) {
    const float* z   = (const float*)d_in[0];
    const float* emb = (const float*)d_in[1];

    float* out0     = (float*)d_out;
    float* out_ids  = out0 + (size_t)NROWS * DDIM;
    float* out_loss = out_ids + NROWS;

    char* ws = (char*)d_ws;
    float* ee   = (float*)(ws + EE_OFF);
    float* zzws = (float*)(ws + ZZ_OFF);
    float* part = (float*)(ws + PART_OFF);

    ee_kernel<<<KCODES, 256, 0, stream>>>(emb, ee);
    zz_kernel<<<NROWS / 4, 256, 0, stream>>>(z, zzws);

    if (ws_size >= WS_NEED) {
        ushort_t* Ab   = (ushort_t*)(ws + AB_OFF);
        ushort_t* Bb   = (ushort_t*)(ws + BB_OFF);
        ushort_t* dtil = (ushort_t*)(ws + DT_OFF);
        split_kernel<<<(NROWS * DDIM / 4) / 256, 256, 0, stream>>>(z, Ab);
        split_kernel<<<(KCODES * DDIM / 4) / 256, 256, 0, stream>>>(emb, Bb);
        mfma_kernel<<<(NROWS / 128) * (KCODES / 128), 256, 0, stream>>>(Ab, Bb, ee, dtil);
        select_kernel<<<NROWS, 256, 0, stream>>>(dtil, ee, zzws, z, emb, out_ids);
    } else {
        float* pval = (float*)(ws + PV_OFF);
        int*   pidx = (int*)(ws + PV_OFF + 131072);
        argmin_kernel<<<(NROWS / BM) * SPLITC, 256, 0, stream>>>(z, emb, ee, zzws, pval, pidx);
        combine_kernel<<<NROWS / 256, 256, 0, stream>>>(pval, pidx, out_ids);
    }

    gather_kernel<<<NROWS / 16, 256, 0, stream>>>(z, emb, out_ids, out0, part);
    loss_kernel<<<1, 256, 0, stream>>>(part, out_loss);
}

// Round 5
// 257.384 us; speedup vs baseline: 4.4412x; 1.2647x over previous
//
#include <hip/hip_runtime.h>
#include <float.h>

typedef unsigned short ushort_t;
typedef unsigned int uint_t;

// Problem constants
#define NROWS 16384   // 8*2048
#define DDIM  768
#define KCODES 2048
#define NCB    16     // code blocks (2048/128)
#define MARGIN 8e-4f

// bf16 helpers (RNE)
__device__ __forceinline__ ushort_t f2bf(float x) {
    uint_t u = __float_as_uint(x);
    uint_t r = (u + 0x7fffu + ((u >> 16) & 1u)) >> 16;
    return (ushort_t)r;
}
__device__ __forceinline__ float bf2f(ushort_t h) {
    return __uint_as_float(((uint_t)h) << 16);
}

// ---------------- ee[c] (UNCHANGED — comparator input, frozen) -------------
__global__ void ee_kernel(const float* __restrict__ emb, float* __restrict__ ee) {
    int c = blockIdx.x;
    const float* e = emb + (size_t)c * DDIM;
    int t = threadIdx.x;
    float s = 0.f;
    for (int i = t; i < DDIM; i += 256) { float v = e[i]; s += v * v; }
    for (int off = 32; off; off >>= 1) s += __shfl_down(s, off);
    __shared__ float red[4];
    if ((t & 63) == 0) red[t >> 6] = s;
    __syncthreads();
    if (t == 0) ee[c] = red[0] + red[1] + red[2] + red[3];
}

// ---------------- zz[r] (UNCHANGED — comparator input, frozen) -------------
__global__ void zz_kernel(const float* __restrict__ z, float* __restrict__ zz) {
    const int t = threadIdx.x;
    const int row = blockIdx.x * 4 + (t >> 6);
    const int lane = t & 63;
    const float* zr = z + (size_t)row * DDIM;
    float s = 0.f;
    for (int i = lane; i < DDIM; i += 64) { float v = zr[i]; s += v * v; }
    for (int off = 32; off; off >>= 1) s += __shfl_down(s, off);
    if (lane == 0) zz[row] = s;
}

// ---------------- convert fp32 -> bf16 (hi only) ---------------------------
__global__ void conv_kernel(const float* __restrict__ src, ushort_t* __restrict__ dst) {
    const int i = blockIdx.x * 256 + threadIdx.x;
    const float4 v = ((const float4*)src)[i];
    ushort4 h;
    h.x = f2bf(v.x); h.y = f2bf(v.y); h.z = f2bf(v.z); h.w = f2bf(v.w);
    ((ushort4*)dst)[i] = h;
}

// ---------------- Phase 1: bf16 MFMA GEMM (K=768) + fused candidate epilogue
typedef __attribute__((ext_vector_type(8))) short bf16x8;
typedef __attribute__((ext_vector_type(4))) float f32x4;

__device__ __forceinline__ int swz(int r) { return (r & 3) ^ ((r >> 2) & 3); }

__global__ __launch_bounds__(256)
void mfma_kernel(const ushort_t* __restrict__ Ab, const ushort_t* __restrict__ Bb,
                 const float* __restrict__ ee, float* __restrict__ bmin,
                 float2* __restrict__ slots) {
    __shared__ ushort_t Als[128 * 32];
    __shared__ ushort_t Bls[128 * 32];
    __shared__ float rowmin[128];
    __shared__ int   rcnt[128];
    __shared__ float sval[128][8];
    __shared__ int   sidx[128][8];

    const int t = threadIdx.x;
    const int w = t >> 6, l = t & 63;
    const int bx = blockIdx.x & 127, by = blockIdx.x >> 7;
    const int row0 = bx << 7, col0 = by << 7;

    f32x4 acc[4][4];
    #pragma unroll
    for (int i = 0; i < 4; ++i)
        #pragma unroll
        for (int j = 0; j < 4; ++j) acc[i][j] = (f32x4){0.f, 0.f, 0.f, 0.f};

    const int sri  = l >> 2;
    const int slot = l & 3;
    const int rha = (w & 1) << 6;
    const int rhb = (w >> 1) << 6;

    for (int kt = 0; kt < 24; ++kt) {
        const int kb = kt << 5;
        __syncthreads();
        #pragma unroll
        for (int q = 0; q < 2; ++q) {
            const int r0 = ((w << 1) + q) << 4;
            const int ra = r0 + sri;
            const int c  = slot ^ swz(ra);
            const ushort_t* gpa = Ab + (size_t)(row0 + ra) * DDIM + kb + (c << 3);
            __builtin_amdgcn_global_load_lds(
                (const __attribute__((address_space(1))) void*)gpa,
                (__attribute__((address_space(3))) void*)((char*)Als + (r0 << 6)), 16, 0, 0);
            const ushort_t* gpb = Bb + (size_t)(col0 + ra) * DDIM + kb + (c << 3);
            __builtin_amdgcn_global_load_lds(
                (const __attribute__((address_space(1))) void*)gpb,
                (__attribute__((address_space(3))) void*)((char*)Bls + (r0 << 6)), 16, 0, 0);
        }
        __syncthreads();

        bf16x8 af[4], bfr[4];
        #pragma unroll
        for (int mi = 0; mi < 4; ++mi) {
            const int r = rha + (mi << 4) + (l & 15);
            const int s = (l >> 4) ^ swz(r);
            af[mi] = *(const bf16x8*)&Als[(r << 5) + (s << 3)];
        }
        #pragma unroll
        for (int ni = 0; ni < 4; ++ni) {
            const int r = rhb + (ni << 4) + (l & 15);
            const int s = (l >> 4) ^ swz(r);
            bfr[ni] = *(const bf16x8*)&Bls[(r << 5) + (s << 3)];
        }
        #pragma unroll
        for (int mi = 0; mi < 4; ++mi)
            #pragma unroll
            for (int ni = 0; ni < 4; ++ni)
                acc[mi][ni] = __builtin_amdgcn_mfma_f32_16x16x32_bf16(
                    af[mi], bfr[ni], acc[mi][ni], 0, 0, 0);
    }

    // ---- epilogue: d~ = ee - 2*dot~ (fp32), per-row block-min + candidates
    // C/D map: row = rha + mi*16 + (l>>4)*4 + r,  col = rhb + ni*16 + (l&15)
    float ecv[4];
    #pragma unroll
    for (int ni = 0; ni < 4; ++ni) ecv[ni] = ee[col0 + rhb + (ni << 4) + (l & 15)];
    #pragma unroll
    for (int mi = 0; mi < 4; ++mi)
        #pragma unroll
        for (int ni = 0; ni < 4; ++ni)
            #pragma unroll
            for (int r = 0; r < 4; ++r)
                acc[mi][ni][r] = ecv[ni] - 2.0f * acc[mi][ni][r];

    // per-(mi,r) min over ni then over the 16-lane col group (xor 1,2,4,8)
    float vmr[4][4];
    #pragma unroll
    for (int mi = 0; mi < 4; ++mi)
        #pragma unroll
        for (int r = 0; r < 4; ++r) {
            float v = fminf(fminf(acc[mi][0][r], acc[mi][1][r]),
                            fminf(acc[mi][2][r], acc[mi][3][r]));
            v = fminf(v, __shfl_xor(v, 1));
            v = fminf(v, __shfl_xor(v, 2));
            v = fminf(v, __shfl_xor(v, 4));
            v = fminf(v, __shfl_xor(v, 8));
            vmr[mi][r] = v;
        }

    if (t < 128) { rowmin[t] = FLT_MAX; rcnt[t] = 0; }
    __syncthreads();
    if (w < 2 && (l & 15) == 0) {
        #pragma unroll
        for (int mi = 0; mi < 4; ++mi)
            #pragma unroll
            for (int r = 0; r < 4; ++r)
                rowmin[rha + (mi << 4) + ((l >> 4) << 2) + r] = vmr[mi][r];
    }
    __syncthreads();
    if (w >= 2 && (l & 15) == 0) {
        #pragma unroll
        for (int mi = 0; mi < 4; ++mi)
            #pragma unroll
            for (int r = 0; r < 4; ++r) {
                const int m = rha + (mi << 4) + ((l >> 4) << 2) + r;
                rowmin[m] = fminf(rowmin[m], vmr[mi][r]);
            }
    }
    __syncthreads();

    #pragma unroll
    for (int mi = 0; mi < 4; ++mi)
        #pragma unroll
        for (int r = 0; r < 4; ++r) {
            const int m = rha + (mi << 4) + ((l >> 4) << 2) + r;
            const float lim = rowmin[m] + MARGIN;
            #pragma unroll
            for (int ni = 0; ni < 4; ++ni) {
                const float vv = acc[mi][ni][r];
                if (vv <= lim) {
                    const int p = atomicAdd(&rcnt[m], 1);
                    if (p < 8) {
                        sval[m][p] = vv;
                        sidx[m][p] = col0 + rhb + (ni << 4) + (l & 15);
                    }
                }
            }
        }
    __syncthreads();

    if (t < 128) {
        const int row = row0 + t;
        bmin[(size_t)by * NROWS + row] = rowmin[t];
        const int n = rcnt[t] < 8 ? rcnt[t] : 8;
        float2 rec[8];
        #pragma unroll
        for (int s2 = 0; s2 < 8; ++s2)
            rec[s2] = (s2 < n) ? make_float2(sval[t][s2], __int_as_float(sidx[t][s2]))
                               : make_float2(FLT_MAX, __int_as_float(0x7fffffff));
        float4* dst = (float4*)(slots + ((size_t)by * NROWS + row) * 8);
        dst[0] = make_float4(rec[0].x, rec[0].y, rec[1].x, rec[1].y);
        dst[1] = make_float4(rec[2].x, rec[2].y, rec[3].x, rec[3].y);
        dst[2] = make_float4(rec[4].x, rec[4].y, rec[5].x, rec[5].y);
        dst[3] = make_float4(rec[6].x, rec[6].y, rec[7].x, rec[7].y);
    }
}

// ---------------- Phase 2: combine + EXACT fp32 re-check (1 wave/row) ------
__global__ __launch_bounds__(256)
void combine_select(const float* __restrict__ bmin, const float2* __restrict__ slots,
                    const float* __restrict__ ee, const float* __restrict__ zz,
                    const float* __restrict__ z, const float* __restrict__ emb,
                    float* __restrict__ ids_f32) {
    const int t = threadIdx.x;
    const int row = blockIdx.x * 4 + (t >> 6);
    const int l = t & 63;

    float v = (l < NCB) ? bmin[(size_t)l * NROWS + row] : FLT_MAX;
    v = fminf(v, __shfl_xor(v, 8));
    v = fminf(v, __shfl_xor(v, 4));
    v = fminf(v, __shfl_xor(v, 2));
    v = fminf(v, __shfl_xor(v, 1));
    const float T = __shfl(v, 0) + MARGIN;

    // lane l covers slots 2l, 2l+1 of the 16x8 slot table
    const int blk = l >> 2;
    const int s0 = (l << 1) & 7;
    const float2* sp = slots + ((size_t)blk * NROWS + row) * 8 + s0;
    const float2 a  = sp[0];
    const float2 b2 = sp[1];

    unsigned long long m0 = __ballot(a.x <= T);
    unsigned long long m1 = __ballot(b2.x <= T);

    const float zzr = zz[row];
    const float* zr = z + (size_t)row * DDIM;

    float bestd = FLT_MAX; int besti = 0x7fffffff;
    while (m0 | m1) {
        int j; float iv;
        if (m0) { j = __ffsll(m0) - 1; m0 &= m0 - 1; iv = a.y; }
        else    { j = __ffsll(m1) - 1; m1 &= m1 - 1; iv = b2.y; }
        const int idx = __float_as_int(__shfl(iv, j));
        const float* er = emb + (size_t)idx * DDIM;
        float p = 0.f;
        #pragma unroll
        for (int k = 0; k < 12; ++k) p += zr[l + 64 * k] * er[l + 64 * k];
        for (int off = 32; off; off >>= 1) p += __shfl_down(p, off);
        if (l == 0) {
            const float t1 = zzr + ee[idx];     // fp32 round (ref order)
            const float d  = t1 - 2.0f * p;     // fp32 round
            if (d < bestd || (d == bestd && idx < besti)) { bestd = d; besti = idx; }
        }
    }
    if (l == 0) ids_f32[row] = (float)besti;
}

// ---------------- gather + straight-through + loss partials (div-free) -----
__global__ __launch_bounds__(256)
void gather_kernel(const float* __restrict__ z, const float* __restrict__ emb,
                   const float* __restrict__ ids_f32, float* __restrict__ out0,
                   float* __restrict__ part) {
    const int b = blockIdx.x;       // 1024 blocks x 16 rows
    const int t = threadIdx.x;
    const int rl = t >> 4, c = t & 15;
    __shared__ int ids[16];
    if (t < 16) ids[t] = (int)ids_f32[b * 16 + t];
    __syncthreads();
    const int row = b * 16 + rl;
    const float4* zr = (const float4*)(z + (size_t)row * DDIM);
    float4* orow = (float4*)(out0 + (size_t)row * DDIM);
    const float4* er = (const float4*)(emb + (size_t)ids[rl] * DDIM);
    float s = 0.f;
    #pragma unroll
    for (int j = 0; j < 12; ++j) {
        const int i4 = c + 16 * j;
        const float4 zv = zr[i4];
        const float4 ev = er[i4];
        float4 o;
        o.x = zv.x + (ev.x - zv.x); o.y = zv.y + (ev.y - zv.y);
        o.z = zv.z + (ev.z - zv.z); o.w = zv.w + (ev.w - zv.w);
        orow[i4] = o;
        float dx = zv.x - ev.x, dy = zv.y - ev.y, dz = zv.z - ev.z, dw = zv.w - ev.w;
        s += dx * dx + dy * dy + dz * dz + dw * dw;
    }
    for (int off = 32; off; off >>= 1) s += __shfl_down(s, off);
    __shared__ float red[4];
    if ((t & 63) == 0) red[t >> 6] = s;
    __syncthreads();
    if (t == 0) part[b] = red[0] + red[1] + red[2] + red[3];
}

__global__ void loss_kernel(const float* __restrict__ part, float* __restrict__ out_loss) {
    const int t = threadIdx.x;
    double s = 0.0;
    for (int i = t; i < 1024; i += 256) s += (double)part[i];
    for (int off = 32; off; off >>= 1) s += __shfl_down(s, off);
    __shared__ double red[4];
    if ((t & 63) == 0) red[t >> 6] = s;
    __syncthreads();
    if (t == 0) {
        const double total = red[0] + red[1] + red[2] + red[3];
        out_loss[0] = (float)(0.25 * (total / (double)((size_t)NROWS * DDIM)));
    }
}

// ================= Fallback (round-3 exact fp32 path, proven) ==============
#define BM 32
#define BN 128
#define BKS 32
#define SPLITC 2
#define CODES_PER_BLOCK (KCODES / SPLITC)
#define NCHUNK (CODES_PER_BLOCK / BN)
#define NSTAGE (DDIM / BKS)
#define APADR 33
#define BPADC 132

__global__ __launch_bounds__(256)
void argmin_kernel(const float* __restrict__ z, const float* __restrict__ emb,
                   const float* __restrict__ ee, const float* __restrict__ zz,
                   float* __restrict__ pval, int* __restrict__ pidx) {
    __shared__ float Af[BKS][APADR];
    __shared__ float Bf[BKS][BPADC];
    __shared__ float cval[BM][33];
    __shared__ int   cidx[BM][33];
    __shared__ float zzs[BM];
    const int t = threadIdx.x;
    const int part = blockIdx.x & (SPLITC - 1);
    const int rb = blockIdx.x >> 1;
    const int row0 = rb * BM;
    const int cbase = part * CODES_PER_BLOCK;
    const int tx = t & 31, ty = t >> 5;
    const int sr = t >> 3;
    const int sk = 4 * (t & 7);
    if (t < BM) zzs[t] = zz[row0 + t];
    float bv[4]; int bi[4];
    #pragma unroll
    for (int i = 0; i < 4; ++i) { bv[i] = FLT_MAX; bi[i] = 0x7fffffff; }
    const float* zt = z + (size_t)(row0 + sr) * DDIM;
    for (int chunk = 0; chunk < NCHUNK; ++chunk) {
        const int c0 = cbase + chunk * BN;
        const float* ebase = emb + (size_t)(c0 + sr) * DDIM;
        float acc[4][4];
        #pragma unroll
        for (int i = 0; i < 4; ++i)
            #pragma unroll
            for (int j = 0; j < 4; ++j) acc[i][j] = 0.f;
        float4 pa = *(const float4*)&zt[sk];
        float4 pb[4];
        #pragma unroll
        for (int m = 0; m < 4; ++m) pb[m] = *(const float4*)&ebase[(size_t)(32 * m) * DDIM + sk];
        for (int s = 0; s < NSTAGE; ++s) {
            __syncthreads();
            Af[sk + 0][sr] = pa.x; Af[sk + 1][sr] = pa.y;
            Af[sk + 2][sr] = pa.z; Af[sk + 3][sr] = pa.w;
            #pragma unroll
            for (int m = 0; m < 4; ++m) {
                Bf[sk + 0][sr + 32 * m] = pb[m].x;
                Bf[sk + 1][sr + 32 * m] = pb[m].y;
                Bf[sk + 2][sr + 32 * m] = pb[m].z;
                Bf[sk + 3][sr + 32 * m] = pb[m].w;
            }
            __syncthreads();
            if (s + 1 < NSTAGE) {
                const int k1 = (s + 1) * BKS + sk;
                pa = *(const float4*)&zt[k1];
                #pragma unroll
                for (int m = 0; m < 4; ++m)
                    pb[m] = *(const float4*)&ebase[(size_t)(32 * m) * DDIM + k1];
            }
            #pragma unroll
            for (int kk = 0; kk < BKS; ++kk) {
                const float4 a4 = *(const float4*)&Af[kk][4 * ty];
                const float4 b4 = *(const float4*)&Bf[kk][4 * tx];
                const float aa[4] = {a4.x, a4.y, a4.z, a4.w};
                const float bb[4] = {b4.x, b4.y, b4.z, b4.w};
                #pragma unroll
                for (int i = 0; i < 4; ++i)
                    #pragma unroll
                    for (int j = 0; j < 4; ++j) acc[i][j] += aa[i] * bb[j];
            }
        }
        const float4 e4 = *(const float4*)&ee[c0 + 4 * tx];
        const float eev[4] = {e4.x, e4.y, e4.z, e4.w};
        #pragma unroll
        for (int i = 0; i < 4; ++i) {
            const float zzr = zzs[4 * ty + i];
            #pragma unroll
            for (int j = 0; j < 4; ++j) {
                const int code = c0 + 4 * tx + j;
                const float t1 = zzr + eev[j];
                const float d  = t1 - 2.0f * acc[i][j];
                if (d < bv[i] || (d == bv[i] && code < bi[i])) { bv[i] = d; bi[i] = code; }
            }
        }
    }
    __syncthreads();
    #pragma unroll
    for (int i = 0; i < 4; ++i) { cval[4 * ty + i][tx] = bv[i]; cidx[4 * ty + i][tx] = bi[i]; }
    __syncthreads();
    if (t < BM) {
        float v = FLT_MAX; int id = 0x7fffffff;
        #pragma unroll
        for (int x = 0; x < 32; ++x) {
            const float cv = cval[t][x]; const int ci = cidx[t][x];
            if (cv < v || (cv == v && ci < id)) { v = cv; id = ci; }
        }
        pval[part * NROWS + row0 + t] = v;
        pidx[part * NROWS + row0 + t] = id;
    }
}

__global__ void combine_kernel(const float* __restrict__ pval, const int* __restrict__ pidx,
                               float* __restrict__ ids_f32) {
    const int r = blockIdx.x * 256 + threadIdx.x;
    float v = pval[r];           int id = pidx[r];
    const float v1 = pval[NROWS + r]; const int i1 = pidx[NROWS + r];
    if (v1 < v || (v1 == v && i1 < id)) { v = v1; id = i1; }
    ids_f32[r] = (float)id;
}

// ================= launch ==================================================
#define EE_OFF   0
#define ZZ_OFF   8192
#define PART_OFF 73728
#define PV_OFF   81920
#define EH_OFF   81920                                   // fallback PV aliases (exclusive paths)
#define ZH_OFF   (EH_OFF + (size_t)KCODES * DDIM * 2)    // +3145728
#define BMIN_OFF (ZH_OFF + (size_t)NROWS * DDIM * 2)     // +25165824
#define SLOT_OFF (BMIN_OFF + (size_t)NCB * NROWS * 4)    // +1048576
#define WS_NEED  (SLOT_OFF + (size_t)NCB * NROWS * 8 * 8) // ~46.2 MB

extern "C" void kernel_launch(void* const* d_in, const int* in_sizes, int n_in,
                              void* d_out, int out_size, void* d_ws, size_t ws_size,
                              hipStream_t stream) {
    const float* z   = (const float*)d_in[0];
    const float* emb = (const float*)d_in[1];

    float* out0     = (float*)d_out;
    float* out_ids  = out0 + (size_t)NROWS * DDIM;
    float* out_loss = out_ids + NROWS;

    char* ws = (char*)d_ws;
    float* ee   = (float*)(ws + EE_OFF);
    float* zzws = (float*)(ws + ZZ_OFF);
    float* part = (float*)(ws + PART_OFF);

    ee_kernel<<<KCODES, 256, 0, stream>>>(emb, ee);
    zz_kernel<<<NROWS / 4, 256, 0, stream>>>(z, zzws);

    if (ws_size >= WS_NEED) {
        ushort_t* Eh   = (ushort_t*)(ws + EH_OFF);
        ushort_t* Zh   = (ushort_t*)(ws + ZH_OFF);
        float*    bmin = (float*)(ws + BMIN_OFF);
        float2*   slot = (float2*)(ws + SLOT_OFF);
        conv_kernel<<<(KCODES * DDIM / 4) / 256, 256, 0, stream>>>(emb, Eh);
        conv_kernel<<<(NROWS * DDIM / 4) / 256, 256, 0, stream>>>(z, Zh);
        mfma_kernel<<<(NROWS / 128) * NCB, 256, 0, stream>>>(Zh, Eh, ee, bmin, slot);
        combine_select<<<NROWS / 4, 256, 0, stream>>>(bmin, slot, ee, zzws, z, emb, out_ids);
    } else {
        float* pval = (float*)(ws + PV_OFF);
        int*   pidx = (int*)(ws + PV_OFF + 131072);
        argmin_kernel<<<(NROWS / BM) * SPLITC, 256, 0, stream>>>(z, emb, ee, zzws, pval, pidx);
        combine_kernel<<<NROWS / 256, 256, 0, stream>>>(pval, pidx, out_ids);
    }

    gather_kernel<<<NROWS / 16, 256, 0, stream>>>(z, emb, out_ids, out0, part);
    loss_kernel<<<1, 256, 0, stream>>>(part, out_loss);
}

// Round 6
// 249.329 us; speedup vs baseline: 4.5847x; 1.0323x over previous
//
#include <hip/hip_runtime.h>
#include <float.h>

typedef unsigned short ushort_t;
typedef unsigned int uint_t;

// Problem constants
#define NROWS 16384   // 8*2048
#define DDIM  768
#define KCODES 2048
#define NCB    16     // code blocks (2048/128)
#define MARGIN 8e-4f

// bf16 helpers (RNE)
__device__ __forceinline__ ushort_t f2bf(float x) {
    uint_t u = __float_as_uint(x);
    uint_t r = (u + 0x7fffu + ((u >> 16) & 1u)) >> 16;
    return (ushort_t)r;
}
__device__ __forceinline__ float bf2f(ushort_t h) {
    return __uint_as_float(((uint_t)h) << 16);
}

// ---------------- prep_emb: ee[c] (frozen math) + bf16 convert -------------
__global__ void prep_emb(const float* __restrict__ emb, float* __restrict__ ee,
                         ushort_t* __restrict__ Eh) {
    int c = blockIdx.x;
    const float* e = emb + (size_t)c * DDIM;
    int t = threadIdx.x;
    float s = 0.f;
    for (int i = t; i < DDIM; i += 256) { float v = e[i]; s += v * v; }
    for (int off = 32; off; off >>= 1) s += __shfl_down(s, off);
    __shared__ float red[4];
    if ((t & 63) == 0) red[t >> 6] = s;
    __syncthreads();
    if (t == 0) ee[c] = red[0] + red[1] + red[2] + red[3];
    if (t < 192) {
        const float4 v = ((const float4*)e)[t];
        ushort4 h;
        h.x = f2bf(v.x); h.y = f2bf(v.y); h.z = f2bf(v.z); h.w = f2bf(v.w);
        ((ushort4*)(Eh + (size_t)c * DDIM))[t] = h;
    }
}

// ---------------- prep_z: zz[r] (frozen math) + bf16 convert ---------------
__global__ void prep_z(const float* __restrict__ z, float* __restrict__ zz,
                       ushort_t* __restrict__ Zh) {
    const int t = threadIdx.x;
    const int row = blockIdx.x * 4 + (t >> 6);
    const int lane = t & 63;
    const float* zr = z + (size_t)row * DDIM;
    float s = 0.f;
    for (int i = lane; i < DDIM; i += 64) { float v = zr[i]; s += v * v; }
    for (int off = 32; off; off >>= 1) s += __shfl_down(s, off);
    if (lane == 0) zz[row] = s;
    const float4* zr4 = (const float4*)zr;
    ushort4* dh = (ushort4*)(Zh + (size_t)row * DDIM);
    #pragma unroll
    for (int j = 0; j < 3; ++j) {
        const int i4 = lane + 64 * j;
        const float4 v = zr4[i4];
        ushort4 h;
        h.x = f2bf(v.x); h.y = f2bf(v.y); h.z = f2bf(v.z); h.w = f2bf(v.w);
        dh[i4] = h;
    }
}

// ---------------- Phase 1: bf16 MFMA GEMM (K=768, BK=64) + fused epilogue --
typedef __attribute__((ext_vector_type(8))) short bf16x8;
typedef __attribute__((ext_vector_type(4))) float f32x4;

__device__ __forceinline__ int swz(int r) { return (r & 3) ^ ((r >> 2) & 3); }

__global__ __launch_bounds__(256)
void mfma_kernel(const ushort_t* __restrict__ Ab, const ushort_t* __restrict__ Bb,
                 const float* __restrict__ ee, float* __restrict__ bmin,
                 float2* __restrict__ slots) {
    // 32 KB tile memory; epilogue arrays alias it (used only after a barrier)
    __shared__ __align__(16) char smem[32768];
    ushort_t* Als = (ushort_t*)smem;            // [2][128*32] bf16 (2 x 8 KB)
    ushort_t* Bls = (ushort_t*)(smem + 16384);  // [2][128*32] bf16
    float* rowmin = (float*)smem;               // 128 (aliased)
    int*   rcnt   = (int*)(smem + 512);         // 128
    float (*sval)[8] = (float(*)[8])(smem + 1024);  // 128x8
    int   (*sidx)[8] = (int(*)[8])(smem + 5120);    // 128x8

    const int t = threadIdx.x;
    const int w = t >> 6, l = t & 63;
    const int bx = blockIdx.x & 127, by = blockIdx.x >> 7;
    const int row0 = bx << 7, col0 = by << 7;

    f32x4 acc[4][4];
    #pragma unroll
    for (int i = 0; i < 4; ++i)
        #pragma unroll
        for (int j = 0; j < 4; ++j) acc[i][j] = (f32x4){0.f, 0.f, 0.f, 0.f};

    const int sri  = l >> 2;
    const int slot = l & 3;
    const int rha = (w & 1) << 6;
    const int rhb = (w >> 1) << 6;

    for (int kt = 0; kt < 12; ++kt) {
        const int kb = kt << 6;     // 64 bf16 per iter, two 32-k sub-tiles
        __syncthreads();
        #pragma unroll
        for (int s = 0; s < 2; ++s) {
            #pragma unroll
            for (int q = 0; q < 2; ++q) {
                const int r0 = ((w << 1) + q) << 4;
                const int ra = r0 + sri;
                const int c  = slot ^ swz(ra);
                const int kk = kb + (s << 5) + (c << 3);
                const ushort_t* gpa = Ab + (size_t)(row0 + ra) * DDIM + kk;
                __builtin_amdgcn_global_load_lds(
                    (const __attribute__((address_space(1))) void*)gpa,
                    (__attribute__((address_space(3))) void*)(smem + (s << 13) + (r0 << 6)),
                    16, 0, 0);
                const ushort_t* gpb = Bb + (size_t)(col0 + ra) * DDIM + kk;
                __builtin_amdgcn_global_load_lds(
                    (const __attribute__((address_space(1))) void*)gpb,
                    (__attribute__((address_space(3))) void*)(smem + 16384 + (s << 13) + (r0 << 6)),
                    16, 0, 0);
            }
        }
        __syncthreads();

        #pragma unroll
        for (int s = 0; s < 2; ++s) {     // same k-order as BK=32 rounds
            bf16x8 af[4], bfr[4];
            #pragma unroll
            for (int mi = 0; mi < 4; ++mi) {
                const int r = rha + (mi << 4) + (l & 15);
                const int sw = (l >> 4) ^ swz(r);
                af[mi] = *(const bf16x8*)&Als[(s << 12) + (r << 5) + (sw << 3)];
            }
            #pragma unroll
            for (int ni = 0; ni < 4; ++ni) {
                const int r = rhb + (ni << 4) + (l & 15);
                const int sw = (l >> 4) ^ swz(r);
                bfr[ni] = *(const bf16x8*)&Bls[(s << 12) + (r << 5) + (sw << 3)];
            }
            #pragma unroll
            for (int mi = 0; mi < 4; ++mi)
                #pragma unroll
                for (int ni = 0; ni < 4; ++ni)
                    acc[mi][ni] = __builtin_amdgcn_mfma_f32_16x16x32_bf16(
                        af[mi], bfr[ni], acc[mi][ni], 0, 0, 0);
        }
    }
    __syncthreads();   // all tile reads done before epilogue aliases smem

    // ---- epilogue: d~ = ee - 2*dot~ (fp32), per-row block-min + candidates
    float ecv[4];
    #pragma unroll
    for (int ni = 0; ni < 4; ++ni) ecv[ni] = ee[col0 + rhb + (ni << 4) + (l & 15)];
    #pragma unroll
    for (int mi = 0; mi < 4; ++mi)
        #pragma unroll
        for (int ni = 0; ni < 4; ++ni)
            #pragma unroll
            for (int r = 0; r < 4; ++r)
                acc[mi][ni][r] = ecv[ni] - 2.0f * acc[mi][ni][r];

    float vmr[4][4];
    #pragma unroll
    for (int mi = 0; mi < 4; ++mi)
        #pragma unroll
        for (int r = 0; r < 4; ++r) {
            float v = fminf(fminf(acc[mi][0][r], acc[mi][1][r]),
                            fminf(acc[mi][2][r], acc[mi][3][r]));
            v = fminf(v, __shfl_xor(v, 1));
            v = fminf(v, __shfl_xor(v, 2));
            v = fminf(v, __shfl_xor(v, 4));
            v = fminf(v, __shfl_xor(v, 8));
            vmr[mi][r] = v;
        }

    if (t < 128) { rowmin[t] = FLT_MAX; rcnt[t] = 0; }
    __syncthreads();
    if (w < 2 && (l & 15) == 0) {
        #pragma unroll
        for (int mi = 0; mi < 4; ++mi)
            #pragma unroll
            for (int r = 0; r < 4; ++r)
                rowmin[rha + (mi << 4) + ((l >> 4) << 2) + r] = vmr[mi][r];
    }
    __syncthreads();
    if (w >= 2 && (l & 15) == 0) {
        #pragma unroll
        for (int mi = 0; mi < 4; ++mi)
            #pragma unroll
            for (int r = 0; r < 4; ++r) {
                const int m = rha + (mi << 4) + ((l >> 4) << 2) + r;
                rowmin[m] = fminf(rowmin[m], vmr[mi][r]);
            }
    }
    __syncthreads();

    #pragma unroll
    for (int mi = 0; mi < 4; ++mi)
        #pragma unroll
        for (int r = 0; r < 4; ++r) {
            const int m = rha + (mi << 4) + ((l >> 4) << 2) + r;
            const float lim = rowmin[m] + MARGIN;
            #pragma unroll
            for (int ni = 0; ni < 4; ++ni) {
                const float vv = acc[mi][ni][r];
                if (vv <= lim) {
                    const int p = atomicAdd(&rcnt[m], 1);
                    if (p < 8) {
                        sval[m][p] = vv;
                        sidx[m][p] = col0 + rhb + (ni << 4) + (l & 15);
                    }
                }
            }
        }
    __syncthreads();

    if (t < 128) {
        const int row = row0 + t;
        bmin[(size_t)by * NROWS + row] = rowmin[t];
        const int n = rcnt[t] < 8 ? rcnt[t] : 8;
        float2 rec[8];
        #pragma unroll
        for (int s2 = 0; s2 < 8; ++s2)
            rec[s2] = (s2 < n) ? make_float2(sval[t][s2], __int_as_float(sidx[t][s2]))
                               : make_float2(FLT_MAX, __int_as_float(0x7fffffff));
        float4* dst = (float4*)(slots + ((size_t)by * NROWS + row) * 8);
        dst[0] = make_float4(rec[0].x, rec[0].y, rec[1].x, rec[1].y);
        dst[1] = make_float4(rec[2].x, rec[2].y, rec[3].x, rec[3].y);
        dst[2] = make_float4(rec[4].x, rec[4].y, rec[5].x, rec[5].y);
        dst[3] = make_float4(rec[6].x, rec[6].y, rec[7].x, rec[7].y);
    }
}

// ------- Phase 2: combine + EXACT fp32 re-check + gather + loss (1 wave/row)
__global__ __launch_bounds__(256)
void combine_select_gather(const float* __restrict__ bmin, const float2* __restrict__ slots,
                           const float* __restrict__ ee, const float* __restrict__ zz,
                           const float* __restrict__ z, const float* __restrict__ emb,
                           float* __restrict__ ids_f32, float* __restrict__ out0,
                           float* __restrict__ rowloss) {
    const int t = threadIdx.x;
    const int row = blockIdx.x * 4 + (t >> 6);
    const int l = t & 63;

    float v = (l < NCB) ? bmin[(size_t)l * NROWS + row] : FLT_MAX;
    v = fminf(v, __shfl_xor(v, 8));
    v = fminf(v, __shfl_xor(v, 4));
    v = fminf(v, __shfl_xor(v, 2));
    v = fminf(v, __shfl_xor(v, 1));
    const float T = __shfl(v, 0) + MARGIN;

    const int blk = l >> 2;
    const int s0 = (l << 1) & 7;
    const float2* sp = slots + ((size_t)blk * NROWS + row) * 8 + s0;
    const float2 a  = sp[0];
    const float2 b2 = sp[1];

    unsigned long long m0 = __ballot(a.x <= T);
    unsigned long long m1 = __ballot(b2.x <= T);

    const float zzr = zz[row];
    const float* zr = z + (size_t)row * DDIM;

    float bestd = FLT_MAX; int besti = 0x7fffffff;
    while (m0 | m1) {
        int j; float iv;
        if (m0) { j = __ffsll(m0) - 1; m0 &= m0 - 1; iv = a.y; }
        else    { j = __ffsll(m1) - 1; m1 &= m1 - 1; iv = b2.y; }
        const int idx = __float_as_int(__shfl(iv, j));
        const float* er = emb + (size_t)idx * DDIM;
        float p = 0.f;
        #pragma unroll
        for (int k = 0; k < 12; ++k) p += zr[l + 64 * k] * er[l + 64 * k];
        for (int off = 32; off; off >>= 1) p += __shfl_down(p, off);
        if (l == 0) {
            const float t1 = zzr + ee[idx];     // fp32 round (ref order)
            const float d  = t1 - 2.0f * p;     // fp32 round
            if (d < bestd || (d == bestd && idx < besti)) { bestd = d; besti = idx; }
        }
    }
    const int bi = __shfl(besti, 0);
    if (l == 0) ids_f32[row] = (float)bi;

    // fused gather + straight-through + per-row loss partial
    const float4* zr4 = (const float4*)zr;
    const float4* er4 = (const float4*)(emb + (size_t)bi * DDIM);
    float4* o4 = (float4*)(out0 + (size_t)row * DDIM);
    float s = 0.f;
    #pragma unroll
    for (int j = 0; j < 3; ++j) {
        const int i4 = l + 64 * j;
        const float4 zv = zr4[i4];
        const float4 ev = er4[i4];
        float4 o;
        o.x = zv.x + (ev.x - zv.x); o.y = zv.y + (ev.y - zv.y);
        o.z = zv.z + (ev.z - zv.z); o.w = zv.w + (ev.w - zv.w);
        o4[i4] = o;
        const float dx = zv.x - ev.x, dy = zv.y - ev.y;
        const float dz = zv.z - ev.z, dw = zv.w - ev.w;
        s += dx * dx + dy * dy + dz * dz + dw * dw;
    }
    for (int off = 32; off; off >>= 1) s += __shfl_down(s, off);
    if (l == 0) rowloss[row] = s;
}

// ---------------- final loss reduction over 16384 row partials -------------
__global__ void loss16k_kernel(const float* __restrict__ rowloss, float* __restrict__ out_loss) {
    const int t = threadIdx.x;
    double s = 0.0;
    for (int i = t; i < NROWS; i += 256) s += (double)rowloss[i];
    for (int off = 32; off; off >>= 1) s += __shfl_down(s, off);
    __shared__ double red[4];
    if ((t & 63) == 0) red[t >> 6] = s;
    __syncthreads();
    if (t == 0) {
        const double total = red[0] + red[1] + red[2] + red[3];
        out_loss[0] = (float)(0.25 * (total / (double)((size_t)NROWS * DDIM)));
    }
}

// ================= Fallback (round-3 exact fp32 path, proven) ==============
__global__ void ee_kernel(const float* __restrict__ emb, float* __restrict__ ee) {
    int c = blockIdx.x;
    const float* e = emb + (size_t)c * DDIM;
    int t = threadIdx.x;
    float s = 0.f;
    for (int i = t; i < DDIM; i += 256) { float v = e[i]; s += v * v; }
    for (int off = 32; off; off >>= 1) s += __shfl_down(s, off);
    __shared__ float red[4];
    if ((t & 63) == 0) red[t >> 6] = s;
    __syncthreads();
    if (t == 0) ee[c] = red[0] + red[1] + red[2] + red[3];
}

__global__ void zz_kernel(const float* __restrict__ z, float* __restrict__ zz) {
    const int t = threadIdx.x;
    const int row = blockIdx.x * 4 + (t >> 6);
    const int lane = t & 63;
    const float* zr = z + (size_t)row * DDIM;
    float s = 0.f;
    for (int i = lane; i < DDIM; i += 64) { float v = zr[i]; s += v * v; }
    for (int off = 32; off; off >>= 1) s += __shfl_down(s, off);
    if (lane == 0) zz[row] = s;
}

#define BM 32
#define BN 128
#define BKS 32
#define SPLITC 2
#define CODES_PER_BLOCK (KCODES / SPLITC)
#define NCHUNK (CODES_PER_BLOCK / BN)
#define NSTAGE (DDIM / BKS)
#define APADR 33
#define BPADC 132

__global__ __launch_bounds__(256)
void argmin_kernel(const float* __restrict__ z, const float* __restrict__ emb,
                   const float* __restrict__ ee, const float* __restrict__ zz,
                   float* __restrict__ pval, int* __restrict__ pidx) {
    __shared__ float Af[BKS][APADR];
    __shared__ float Bf[BKS][BPADC];
    __shared__ float cval[BM][33];
    __shared__ int   cidx[BM][33];
    __shared__ float zzs[BM];
    const int t = threadIdx.x;
    const int part = blockIdx.x & (SPLITC - 1);
    const int rb = blockIdx.x >> 1;
    const int row0 = rb * BM;
    const int cbase = part * CODES_PER_BLOCK;
    const int tx = t & 31, ty = t >> 5;
    const int sr = t >> 3;
    const int sk = 4 * (t & 7);
    if (t < BM) zzs[t] = zz[row0 + t];
    float bv[4]; int bi[4];
    #pragma unroll
    for (int i = 0; i < 4; ++i) { bv[i] = FLT_MAX; bi[i] = 0x7fffffff; }
    const float* zt = z + (size_t)(row0 + sr) * DDIM;
    for (int chunk = 0; chunk < NCHUNK; ++chunk) {
        const int c0 = cbase + chunk * BN;
        const float* ebase = emb + (size_t)(c0 + sr) * DDIM;
        float acc[4][4];
        #pragma unroll
        for (int i = 0; i < 4; ++i)
            #pragma unroll
            for (int j = 0; j < 4; ++j) acc[i][j] = 0.f;
        float4 pa = *(const float4*)&zt[sk];
        float4 pb[4];
        #pragma unroll
        for (int m = 0; m < 4; ++m) pb[m] = *(const float4*)&ebase[(size_t)(32 * m) * DDIM + sk];
        for (int s = 0; s < NSTAGE; ++s) {
            __syncthreads();
            Af[sk + 0][sr] = pa.x; Af[sk + 1][sr] = pa.y;
            Af[sk + 2][sr] = pa.z; Af[sk + 3][sr] = pa.w;
            #pragma unroll
            for (int m = 0; m < 4; ++m) {
                Bf[sk + 0][sr + 32 * m] = pb[m].x;
                Bf[sk + 1][sr + 32 * m] = pb[m].y;
                Bf[sk + 2][sr + 32 * m] = pb[m].z;
                Bf[sk + 3][sr + 32 * m] = pb[m].w;
            }
            __syncthreads();
            if (s + 1 < NSTAGE) {
                const int k1 = (s + 1) * BKS + sk;
                pa = *(const float4*)&zt[k1];
                #pragma unroll
                for (int m = 0; m < 4; ++m)
                    pb[m] = *(const float4*)&ebase[(size_t)(32 * m) * DDIM + k1];
            }
            #pragma unroll
            for (int kk = 0; kk < BKS; ++kk) {
                const float4 a4 = *(const float4*)&Af[kk][4 * ty];
                const float4 b4 = *(const float4*)&Bf[kk][4 * tx];
                const float aa[4] = {a4.x, a4.y, a4.z, a4.w};
                const float bb[4] = {b4.x, b4.y, b4.z, b4.w};
                #pragma unroll
                for (int i = 0; i < 4; ++i)
                    #pragma unroll
                    for (int j = 0; j < 4; ++j) acc[i][j] += aa[i] * bb[j];
            }
        }
        const float4 e4 = *(const float4*)&ee[c0 + 4 * tx];
        const float eev[4] = {e4.x, e4.y, e4.z, e4.w};
        #pragma unroll
        for (int i = 0; i < 4; ++i) {
            const float zzr = zzs[4 * ty + i];
            #pragma unroll
            for (int j = 0; j < 4; ++j) {
                const int code = c0 + 4 * tx + j;
                const float t1 = zzr + eev[j];
                const float d  = t1 - 2.0f * acc[i][j];
                if (d < bv[i] || (d == bv[i] && code < bi[i])) { bv[i] = d; bi[i] = code; }
            }
        }
    }
    __syncthreads();
    #pragma unroll
    for (int i = 0; i < 4; ++i) { cval[4 * ty + i][tx] = bv[i]; cidx[4 * ty + i][tx] = bi[i]; }
    __syncthreads();
    if (t < BM) {
        float v = FLT_MAX; int id = 0x7fffffff;
        #pragma unroll
        for (int x = 0; x < 32; ++x) {
            const float cv = cval[t][x]; const int ci = cidx[t][x];
            if (cv < v || (cv == v && ci < id)) { v = cv; id = ci; }
        }
        pval[part * NROWS + row0 + t] = v;
        pidx[part * NROWS + row0 + t] = id;
    }
}

__global__ void combine_kernel(const float* __restrict__ pval, const int* __restrict__ pidx,
                               float* __restrict__ ids_f32) {
    const int r = blockIdx.x * 256 + threadIdx.x;
    float v = pval[r];           int id = pidx[r];
    const float v1 = pval[NROWS + r]; const int i1 = pidx[NROWS + r];
    if (v1 < v || (v1 == v && i1 < id)) { v = v1; id = i1; }
    ids_f32[r] = (float)id;
}

__global__ __launch_bounds__(256)
void gather_kernel(const float* __restrict__ z, const float* __restrict__ emb,
                   const float* __restrict__ ids_f32, float* __restrict__ out0,
                   float* __restrict__ part) {
    const int b = blockIdx.x;
    const int t = threadIdx.x;
    const int rl = t >> 4, c = t & 15;
    __shared__ int ids[16];
    if (t < 16) ids[t] = (int)ids_f32[b * 16 + t];
    __syncthreads();
    const int row = b * 16 + rl;
    const float4* zr = (const float4*)(z + (size_t)row * DDIM);
    float4* orow = (float4*)(out0 + (size_t)row * DDIM);
    const float4* er = (const float4*)(emb + (size_t)ids[rl] * DDIM);
    float s = 0.f;
    #pragma unroll
    for (int j = 0; j < 12; ++j) {
        const int i4 = c + 16 * j;
        const float4 zv = zr[i4];
        const float4 ev = er[i4];
        float4 o;
        o.x = zv.x + (ev.x - zv.x); o.y = zv.y + (ev.y - zv.y);
        o.z = zv.z + (ev.z - zv.z); o.w = zv.w + (ev.w - zv.w);
        orow[i4] = o;
        float dx = zv.x - ev.x, dy = zv.y - ev.y, dz = zv.z - ev.z, dw = zv.w - ev.w;
        s += dx * dx + dy * dy + dz * dz + dw * dw;
    }
    for (int off = 32; off; off >>= 1) s += __shfl_down(s, off);
    __shared__ float red[4];
    if ((t & 63) == 0) red[t >> 6] = s;
    __syncthreads();
    if (t == 0) part[b] = red[0] + red[1] + red[2] + red[3];
}

__global__ void loss_kernel(const float* __restrict__ part, float* __restrict__ out_loss) {
    const int t = threadIdx.x;
    double s = 0.0;
    for (int i = t; i < 1024; i += 256) s += (double)part[i];
    for (int off = 32; off; off >>= 1) s += __shfl_down(s, off);
    __shared__ double red[4];
    if ((t & 63) == 0) red[t >> 6] = s;
    __syncthreads();
    if (t == 0) {
        const double total = red[0] + red[1] + red[2] + red[3];
        out_loss[0] = (float)(0.25 * (total / (double)((size_t)NROWS * DDIM)));
    }
}

// ================= launch ==================================================
#define EE_OFF   0
#define ZZ_OFF   8192
#define RL_OFF   73728                                       // 16384 f32 rowloss
#define EH_OFF   139264                                      // bf16 emb
#define ZH_OFF   (EH_OFF + (size_t)KCODES * DDIM * 2)        // bf16 z
#define BMIN_OFF (ZH_OFF + (size_t)NROWS * DDIM * 2)
#define SLOT_OFF (BMIN_OFF + (size_t)NCB * NROWS * 4)
#define WS_NEED  (SLOT_OFF + (size_t)NCB * NROWS * 8 * 8)    // ~44.1 MB
#define PV_OFF   81920                                       // fallback (exclusive)

extern "C" void kernel_launch(void* const* d_in, const int* in_sizes, int n_in,
                              void* d_out, int out_size, void* d_ws, size_t ws_size,
                              hipStream_t stream) {
    const float* z   = (const float*)d_in[0];
    const float* emb = (const float*)d_in[1];

    float* out0     = (float*)d_out;
    float* out_ids  = out0 + (size_t)NROWS * DDIM;
    float* out_loss = out_ids + NROWS;

    char* ws = (char*)d_ws;
    float* ee   = (float*)(ws + EE_OFF);
    float* zzws = (float*)(ws + ZZ_OFF);

    if (ws_size >= WS_NEED) {
        ushort_t* Eh   = (ushort_t*)(ws + EH_OFF);
        ushort_t* Zh   = (ushort_t*)(ws + ZH_OFF);
        float*    bmin = (float*)(ws + BMIN_OFF);
        float2*   slot = (float2*)(ws + SLOT_OFF);
        float*    rl   = (float*)(ws + RL_OFF);
        prep_emb<<<KCODES, 256, 0, stream>>>(emb, ee, Eh);
        prep_z<<<NROWS / 4, 256, 0, stream>>>(z, zzws, Zh);
        mfma_kernel<<<(NROWS / 128) * NCB, 256, 0, stream>>>(Zh, Eh, ee, bmin, slot);
        combine_select_gather<<<NROWS / 4, 256, 0, stream>>>(bmin, slot, ee, zzws, z, emb,
                                                             out_ids, out0, rl);
        loss16k_kernel<<<1, 256, 0, stream>>>(rl, out_loss);
    } else {
        float* part = (float*)(ws + RL_OFF);
        float* pval = (float*)(ws + PV_OFF);
        int*   pidx = (int*)(ws + PV_OFF + 131072);
        ee_kernel<<<KCODES, 256, 0, stream>>>(emb, ee);
        zz_kernel<<<NROWS / 4, 256, 0, stream>>>(z, zzws);
        argmin_kernel<<<(NROWS / BM) * SPLITC, 256, 0, stream>>>(z, emb, ee, zzws, pval, pidx);
        combine_kernel<<<NROWS / 256, 256, 0, stream>>>(pval, pidx, out_ids);
        gather_kernel<<<NROWS / 16, 256, 0, stream>>>(z, emb, out_ids, out0, part);
        loss_kernel<<<1, 256, 0, stream>>>(part, out_loss);
    }
}

// Round 8
// 242.177 us; speedup vs baseline: 4.7201x; 1.0295x over previous
//
#include <hip/hip_runtime.h>
#include <float.h>

typedef unsigned short ushort_t;
typedef unsigned int uint_t;

// Problem constants
#define NROWS 16384   // 8*2048
#define DDIM  768
#define KCODES 2048
#define NCB2   8      // code blocks (2048/256)
#define MARGIN 8e-4f

// bf16 helpers (RNE)
__device__ __forceinline__ ushort_t f2bf(float x) {
    uint_t u = __float_as_uint(x);
    uint_t r = (u + 0x7fffu + ((u >> 16) & 1u)) >> 16;
    return (ushort_t)r;
}
__device__ __forceinline__ float bf2f(ushort_t h) {
    return __uint_as_float(((uint_t)h) << 16);
}

// ---------- prep: ee (frozen) + zz (frozen) + bf16 converts + zero loss ----
__global__ void prep_kernel(const float* __restrict__ z, const float* __restrict__ emb,
                            float* __restrict__ ee, float* __restrict__ zz,
                            ushort_t* __restrict__ Zh, ushort_t* __restrict__ Eh,
                            float* __restrict__ out_loss) {
    const int b = blockIdx.x, t = threadIdx.x;
    if (b == 0 && t == 0) out_loss[0] = 0.f;
    if (b < KCODES) {
        const int c = b;
        const float* e = emb + (size_t)c * DDIM;
        float s = 0.f;
        for (int i = t; i < DDIM; i += 256) { float v = e[i]; s += v * v; }
        for (int off = 32; off; off >>= 1) s += __shfl_down(s, off);
        __shared__ float red[4];
        if ((t & 63) == 0) red[t >> 6] = s;
        __syncthreads();
        if (t == 0) ee[c] = red[0] + red[1] + red[2] + red[3];
        if (t < 192) {
            const float4 v = ((const float4*)e)[t];
            ushort4 h;
            h.x = f2bf(v.x); h.y = f2bf(v.y); h.z = f2bf(v.z); h.w = f2bf(v.w);
            ((ushort4*)(Eh + (size_t)c * DDIM))[t] = h;
        }
    } else {
        const int rb = b - KCODES;
        const int row = rb * 4 + (t >> 6);
        const int lane = t & 63;
        const float* zr = z + (size_t)row * DDIM;
        float s = 0.f;
        for (int i = lane; i < DDIM; i += 64) { float v = zr[i]; s += v * v; }
        for (int off = 32; off; off >>= 1) s += __shfl_down(s, off);
        if (lane == 0) zz[row] = s;
        const float4* zr4 = (const float4*)zr;
        ushort4* dh = (ushort4*)(Zh + (size_t)row * DDIM);
        #pragma unroll
        for (int j = 0; j < 3; ++j) {
            const int i4 = lane + 64 * j;
            const float4 v = zr4[i4];
            ushort4 h;
            h.x = f2bf(v.x); h.y = f2bf(v.y); h.z = f2bf(v.z); h.w = f2bf(v.w);
            dh[i4] = h;
        }
    }
}

// ---------------- Phase 1: bf16 MFMA GEMM 128x256, K=768, BK=32 ------------
typedef __attribute__((ext_vector_type(8))) short bf16x8;
typedef __attribute__((ext_vector_type(4))) float f32x4;

__device__ __forceinline__ int swz(int r) { return (r & 3) ^ ((r >> 2) & 3); }

__global__ __launch_bounds__(256, 2)
void mfma_kernel(const ushort_t* __restrict__ Ab, const ushort_t* __restrict__ Bb,
                 const float* __restrict__ ee, float* __restrict__ bmin,
                 float2* __restrict__ slots) {
    // A tile: 0..8191 (128 rows x 64B), B tile: 8192..24575 (256 rows x 64B)
    __shared__ __align__(16) char smem[24576];
    float* rowmin = (float*)smem;                   // aliased epilogue arrays
    int*   rcnt   = (int*)(smem + 512);
    float (*sval)[8] = (float(*)[8])(smem + 1024);
    int   (*sidx)[8] = (int(*)[8])(smem + 5120);

    const int t = threadIdx.x;
    const int w = t >> 6, l = t & 63;
    const int bx = blockIdx.x & 127;   // 128 row-blocks
    const int by = blockIdx.x >> 7;    // 8 col-blocks
    const int row0 = bx << 7;          // *128
    const int col0 = by << 8;          // *256

    f32x4 acc[4][8];
    #pragma unroll
    for (int i = 0; i < 4; ++i)
        #pragma unroll
        for (int j = 0; j < 8; ++j) acc[i][j] = (f32x4){0.f, 0.f, 0.f, 0.f};

    // staging pointers; k advances by incrementing the GLOBAL pointer only.
    // NOTE: the builtin's imm offset applies to BOTH global and LDS address
    // (LLVM IntrinsicsAMDGPU.td) — round-7 bug — so it must stay 0.
    const int sri = l >> 2, slot = l & 3;
    const ushort_t* gA[2]; uint_t lA[2];
    #pragma unroll
    for (int q = 0; q < 2; ++q) {
        const int r0 = ((w << 1) + q) << 4;
        const int ra = r0 + sri;
        const int c  = slot ^ swz(ra);
        gA[q] = Ab + (size_t)(row0 + ra) * DDIM + (c << 3);
        lA[q] = r0 << 6;
    }
    const ushort_t* gB[4]; uint_t lB[4];
    #pragma unroll
    for (int q = 0; q < 4; ++q) {
        const int r0 = ((w << 2) + q) << 4;
        const int ra = r0 + sri;
        const int c  = slot ^ swz(ra);
        gB[q] = Bb + (size_t)(col0 + ra) * DDIM + (c << 3);
        lB[q] = 8192 + (r0 << 6);
    }

    // fragment LDS addresses (fully loop-invariant)
    const int rha = (w & 1) << 6;    // row half (0/64)
    const int chb = (w >> 1) << 7;   // col half (0/128)
    const ushort_t* aAddr[4]; const ushort_t* bAddr[8];
    #pragma unroll
    for (int mi = 0; mi < 4; ++mi) {
        const int r = rha + (mi << 4) + (l & 15);
        const int sw = (l >> 4) ^ swz(r);
        aAddr[mi] = (const ushort_t*)(smem + (r << 6) + (sw << 4));
    }
    #pragma unroll
    for (int ni = 0; ni < 8; ++ni) {
        const int r = chb + (ni << 4) + (l & 15);
        const int sw = (l >> 4) ^ swz(r);
        bAddr[ni] = (const ushort_t*)(smem + 8192 + (r << 6) + (sw << 4));
    }

    for (int kt = 0; kt < 24; ++kt) {       // k-order 0..767, frozen
        __syncthreads();
        #pragma unroll
        for (int q = 0; q < 2; ++q) {
            __builtin_amdgcn_global_load_lds(
                (const __attribute__((address_space(1))) void*)gA[q],
                (__attribute__((address_space(3))) void*)(smem + lA[q]), 16, 0, 0);
            gA[q] += 32;
        }
        #pragma unroll
        for (int q = 0; q < 4; ++q) {
            __builtin_amdgcn_global_load_lds(
                (const __attribute__((address_space(1))) void*)gB[q],
                (__attribute__((address_space(3))) void*)(smem + lB[q]), 16, 0, 0);
            gB[q] += 32;
        }
        __syncthreads();

        bf16x8 af[4], bfr[8];
        #pragma unroll
        for (int mi = 0; mi < 4; ++mi) af[mi] = *(const bf16x8*)aAddr[mi];
        #pragma unroll
        for (int ni = 0; ni < 8; ++ni) bfr[ni] = *(const bf16x8*)bAddr[ni];
        #pragma unroll
        for (int mi = 0; mi < 4; ++mi)
            #pragma unroll
            for (int ni = 0; ni < 8; ++ni)
                acc[mi][ni] = __builtin_amdgcn_mfma_f32_16x16x32_bf16(
                    af[mi], bfr[ni], acc[mi][ni], 0, 0, 0);
    }

    __syncthreads();   // tile reads done before epilogue aliases smem

    // ---- epilogue: d~ = ee - 2*dot~ (fp32, frozen ops), block-min + slots
    float ecv[8];
    #pragma unroll
    for (int ni = 0; ni < 8; ++ni) ecv[ni] = ee[col0 + chb + (ni << 4) + (l & 15)];
    #pragma unroll
    for (int mi = 0; mi < 4; ++mi)
        #pragma unroll
        for (int ni = 0; ni < 8; ++ni)
            #pragma unroll
            for (int r = 0; r < 4; ++r)
                acc[mi][ni][r] = ecv[ni] - 2.0f * acc[mi][ni][r];

    float vmr[4][4];
    #pragma unroll
    for (int mi = 0; mi < 4; ++mi)
        #pragma unroll
        for (int r = 0; r < 4; ++r) {
            float v = acc[mi][0][r];
            #pragma unroll
            for (int ni = 1; ni < 8; ++ni) v = fminf(v, acc[mi][ni][r]);
            v = fminf(v, __shfl_xor(v, 1));
            v = fminf(v, __shfl_xor(v, 2));
            v = fminf(v, __shfl_xor(v, 4));
            v = fminf(v, __shfl_xor(v, 8));
            vmr[mi][r] = v;
        }

    if (t < 128) { rowmin[t] = FLT_MAX; rcnt[t] = 0; }
    __syncthreads();
    if (w < 2 && (l & 15) == 0) {
        #pragma unroll
        for (int mi = 0; mi < 4; ++mi)
            #pragma unroll
            for (int r = 0; r < 4; ++r)
                rowmin[rha + (mi << 4) + ((l >> 4) << 2) + r] = vmr[mi][r];
    }
    __syncthreads();
    if (w >= 2 && (l & 15) == 0) {
        #pragma unroll
        for (int mi = 0; mi < 4; ++mi)
            #pragma unroll
            for (int r = 0; r < 4; ++r) {
                const int m = rha + (mi << 4) + ((l >> 4) << 2) + r;
                rowmin[m] = fminf(rowmin[m], vmr[mi][r]);
            }
    }
    __syncthreads();

    #pragma unroll
    for (int mi = 0; mi < 4; ++mi)
        #pragma unroll
        for (int r = 0; r < 4; ++r) {
            const int m = rha + (mi << 4) + ((l >> 4) << 2) + r;
            const float lim = rowmin[m] + MARGIN;
            #pragma unroll
            for (int ni = 0; ni < 8; ++ni) {
                const float vv = acc[mi][ni][r];
                if (vv <= lim) {
                    const int p = atomicAdd(&rcnt[m], 1);
                    if (p < 8) {
                        sval[m][p] = vv;
                        sidx[m][p] = col0 + chb + (ni << 4) + (l & 15);
                    }
                }
            }
        }
    __syncthreads();

    if (t < 128) {
        const int row = row0 + t;
        bmin[(size_t)by * NROWS + row] = rowmin[t];
        const int n = rcnt[t] < 8 ? rcnt[t] : 8;
        float2 rec[8];
        #pragma unroll
        for (int s2 = 0; s2 < 8; ++s2)
            rec[s2] = (s2 < n) ? make_float2(sval[t][s2], __int_as_float(sidx[t][s2]))
                               : make_float2(FLT_MAX, __int_as_float(0x7fffffff));
        float4* dst = (float4*)(slots + ((size_t)by * NROWS + row) * 8);
        dst[0] = make_float4(rec[0].x, rec[0].y, rec[1].x, rec[1].y);
        dst[1] = make_float4(rec[2].x, rec[2].y, rec[3].x, rec[3].y);
        dst[2] = make_float4(rec[4].x, rec[4].y, rec[5].x, rec[5].y);
        dst[3] = make_float4(rec[6].x, rec[6].y, rec[7].x, rec[7].y);
    }
}

// -- Phase 2: combine + EXACT fp32 re-check (frozen) + gather + loss atomic -
__global__ __launch_bounds__(256)
void combine_select_gather(const float* __restrict__ bmin, const float2* __restrict__ slots,
                           const float* __restrict__ ee, const float* __restrict__ zz,
                           const float* __restrict__ z, const float* __restrict__ emb,
                           float* __restrict__ ids_f32, float* __restrict__ out0,
                           float* __restrict__ out_loss) {
    const int t = threadIdx.x;
    const int w = t >> 6;
    const int row = blockIdx.x * 4 + w;
    const int l = t & 63;

    float v = (l < NCB2) ? bmin[(size_t)l * NROWS + row] : FLT_MAX;
    v = fminf(v, __shfl_xor(v, 4));
    v = fminf(v, __shfl_xor(v, 2));
    v = fminf(v, __shfl_xor(v, 1));
    const float T = __shfl(v, 0) + MARGIN;

    // 64 slots per row (8 blocks x 8) -> exactly one float2 per lane
    const int blk = l >> 3;
    const int s0 = l & 7;
    const float2 a = slots[((size_t)blk * NROWS + row) * 8 + s0];

    unsigned long long m = __ballot(a.x <= T);

    const float zzr = zz[row];
    const float* zr = z + (size_t)row * DDIM;

    float bestd = FLT_MAX; int besti = 0x7fffffff;
    while (m) {
        const int j = __ffsll(m) - 1; m &= m - 1;
        const int idx = __float_as_int(__shfl(a.y, j));
        const float* er = emb + (size_t)idx * DDIM;
        float p = 0.f;
        #pragma unroll
        for (int k = 0; k < 12; ++k) p += zr[l + 64 * k] * er[l + 64 * k];
        for (int off = 32; off; off >>= 1) p += __shfl_down(p, off);
        if (l == 0) {
            const float t1 = zzr + ee[idx];     // fp32 round (ref order)
            const float d  = t1 - 2.0f * p;     // fp32 round
            if (d < bestd || (d == bestd && idx < besti)) { bestd = d; besti = idx; }
        }
    }
    const int bi = __shfl(besti, 0);
    if (l == 0) ids_f32[row] = (float)bi;

    // fused gather + straight-through + loss partial
    const float4* zr4 = (const float4*)zr;
    const float4* er4 = (const float4*)(emb + (size_t)bi * DDIM);
    float4* o4 = (float4*)(out0 + (size_t)row * DDIM);
    float s = 0.f;
    #pragma unroll
    for (int j = 0; j < 3; ++j) {
        const int i4 = l + 64 * j;
        const float4 zv = zr4[i4];
        const float4 ev = er4[i4];
        float4 o;
        o.x = zv.x + (ev.x - zv.x); o.y = zv.y + (ev.y - zv.y);
        o.z = zv.z + (ev.z - zv.z); o.w = zv.w + (ev.w - zv.w);
        o4[i4] = o;
        const float dx = zv.x - ev.x, dy = zv.y - ev.y;
        const float dz = zv.z - ev.z, dw = zv.w - ev.w;
        s += dx * dx + dy * dy + dz * dz + dw * dw;
    }
    for (int off = 32; off; off >>= 1) s += __shfl_down(s, off);
    __shared__ float lred[4];
    if (l == 0) lred[w] = s;
    __syncthreads();
    if (t == 0) {
        const float tot = lred[0] + lred[1] + lred[2] + lred[3];
        atomicAdd(out_loss, tot * (0.25f / (float)((size_t)NROWS * DDIM)));
    }
}

// ================= Fallback (round-3 exact fp32 path, proven) ==============
__global__ void ee_kernel(const float* __restrict__ emb, float* __restrict__ ee) {
    int c = blockIdx.x;
    const float* e = emb + (size_t)c * DDIM;
    int t = threadIdx.x;
    float s = 0.f;
    for (int i = t; i < DDIM; i += 256) { float v = e[i]; s += v * v; }
    for (int off = 32; off; off >>= 1) s += __shfl_down(s, off);
    __shared__ float red[4];
    if ((t & 63) == 0) red[t >> 6] = s;
    __syncthreads();
    if (t == 0) ee[c] = red[0] + red[1] + red[2] + red[3];
}

__global__ void zz_kernel(const float* __restrict__ z, float* __restrict__ zz) {
    const int t = threadIdx.x;
    const int row = blockIdx.x * 4 + (t >> 6);
    const int lane = t & 63;
    const float* zr = z + (size_t)row * DDIM;
    float s = 0.f;
    for (int i = lane; i < DDIM; i += 64) { float v = zr[i]; s += v * v; }
    for (int off = 32; off; off >>= 1) s += __shfl_down(s, off);
    if (lane == 0) zz[row] = s;
}

#define BM 32
#define BN 128
#define BKS 32
#define SPLITC 2
#define CODES_PER_BLOCK (KCODES / SPLITC)
#define NCHUNK (CODES_PER_BLOCK / BN)
#define NSTAGE (DDIM / BKS)
#define APADR 33
#define BPADC 132

__global__ __launch_bounds__(256)
void argmin_kernel(const float* __restrict__ z, const float* __restrict__ emb,
                   const float* __restrict__ ee, const float* __restrict__ zz,
                   float* __restrict__ pval, int* __restrict__ pidx) {
    __shared__ float Af[BKS][APADR];
    __shared__ float Bf[BKS][BPADC];
    __shared__ float cval[BM][33];
    __shared__ int   cidx[BM][33];
    __shared__ float zzs[BM];
    const int t = threadIdx.x;
    const int part = blockIdx.x & (SPLITC - 1);
    const int rb = blockIdx.x >> 1;
    const int row0 = rb * BM;
    const int cbase = part * CODES_PER_BLOCK;
    const int tx = t & 31, ty = t >> 5;
    const int sr = t >> 3;
    const int sk = 4 * (t & 7);
    if (t < BM) zzs[t] = zz[row0 + t];
    float bv[4]; int bi[4];
    #pragma unroll
    for (int i = 0; i < 4; ++i) { bv[i] = FLT_MAX; bi[i] = 0x7fffffff; }
    const float* zt = z + (size_t)(row0 + sr) * DDIM;
    for (int chunk = 0; chunk < NCHUNK; ++chunk) {
        const int c0 = cbase + chunk * BN;
        const float* ebase = emb + (size_t)(c0 + sr) * DDIM;
        float acc[4][4];
        #pragma unroll
        for (int i = 0; i < 4; ++i)
            #pragma unroll
            for (int j = 0; j < 4; ++j) acc[i][j] = 0.f;
        float4 pa = *(const float4*)&zt[sk];
        float4 pb[4];
        #pragma unroll
        for (int m = 0; m < 4; ++m) pb[m] = *(const float4*)&ebase[(size_t)(32 * m) * DDIM + sk];
        for (int s = 0; s < NSTAGE; ++s) {
            __syncthreads();
            Af[sk + 0][sr] = pa.x; Af[sk + 1][sr] = pa.y;
            Af[sk + 2][sr] = pa.z; Af[sk + 3][sr] = pa.w;
            #pragma unroll
            for (int m = 0; m < 4; ++m) {
                Bf[sk + 0][sr + 32 * m] = pb[m].x;
                Bf[sk + 1][sr + 32 * m] = pb[m].y;
                Bf[sk + 2][sr + 32 * m] = pb[m].z;
                Bf[sk + 3][sr + 32 * m] = pb[m].w;
            }
            __syncthreads();
            if (s + 1 < NSTAGE) {
                const int k1 = (s + 1) * BKS + sk;
                pa = *(const float4*)&zt[k1];
                #pragma unroll
                for (int m = 0; m < 4; ++m)
                    pb[m] = *(const float4*)&ebase[(size_t)(32 * m) * DDIM + k1];
            }
            #pragma unroll
            for (int kk = 0; kk < BKS; ++kk) {
                const float4 a4 = *(const float4*)&Af[kk][4 * ty];
                const float4 b4 = *(const float4*)&Bf[kk][4 * tx];
                const float aa[4] = {a4.x, a4.y, a4.z, a4.w};
                const float bb[4] = {b4.x, b4.y, b4.z, b4.w};
                #pragma unroll
                for (int i = 0; i < 4; ++i)
                    #pragma unroll
                    for (int j = 0; j < 4; ++j) acc[i][j] += aa[i] * bb[j];
            }
        }
        const float4 e4 = *(const float4*)&ee[c0 + 4 * tx];
        const float eev[4] = {e4.x, e4.y, e4.z, e4.w};
        #pragma unroll
        for (int i = 0; i < 4; ++i) {
            const float zzr = zzs[4 * ty + i];
            #pragma unroll
            for (int j = 0; j < 4; ++j) {
                const int code = c0 + 4 * tx + j;
                const float t1 = zzr + eev[j];
                const float d  = t1 - 2.0f * acc[i][j];
                if (d < bv[i] || (d == bv[i] && code < bi[i])) { bv[i] = d; bi[i] = code; }
            }
        }
    }
    __syncthreads();
    #pragma unroll
    for (int i = 0; i < 4; ++i) { cval[4 * ty + i][tx] = bv[i]; cidx[4 * ty + i][tx] = bi[i]; }
    __syncthreads();
    if (t < BM) {
        float v = FLT_MAX; int id = 0x7fffffff;
        #pragma unroll
        for (int x = 0; x < 32; ++x) {
            const float cv = cval[t][x]; const int ci = cidx[t][x];
            if (cv < v || (cv == v && ci < id)) { v = cv; id = ci; }
        }
        pval[part * NROWS + row0 + t] = v;
        pidx[part * NROWS + row0 + t] = id;
    }
}

__global__ void combine_kernel(const float* __restrict__ pval, const int* __restrict__ pidx,
                               float* __restrict__ ids_f32) {
    const int r = blockIdx.x * 256 + threadIdx.x;
    float v = pval[r];           int id = pidx[r];
    const float v1 = pval[NROWS + r]; const int i1 = pidx[NROWS + r];
    if (v1 < v || (v1 == v && i1 < id)) { v = v1; id = i1; }
    ids_f32[r] = (float)id;
}

__global__ __launch_bounds__(256)
void gather_kernel(const float* __restrict__ z, const float* __restrict__ emb,
                   const float* __restrict__ ids_f32, float* __restrict__ out0,
                   float* __restrict__ part) {
    const int b = blockIdx.x;
    const int t = threadIdx.x;
    const int rl = t >> 4, c = t & 15;
    __shared__ int ids[16];
    if (t < 16) ids[t] = (int)ids_f32[b * 16 + t];
    __syncthreads();
    const int row = b * 16 + rl;
    const float4* zr = (const float4*)(z + (size_t)row * DDIM);
    float4* orow = (float4*)(out0 + (size_t)row * DDIM);
    const float4* er = (const float4*)(emb + (size_t)ids[rl] * DDIM);
    float s = 0.f;
    #pragma unroll
    for (int j = 0; j < 12; ++j) {
        const int i4 = c + 16 * j;
        const float4 zv = zr[i4];
        const float4 ev = er[i4];
        float4 o;
        o.x = zv.x + (ev.x - zv.x); o.y = zv.y + (ev.y - zv.y);
        o.z = zv.z + (ev.z - zv.z); o.w = zv.w + (ev.w - zv.w);
        orow[i4] = o;
        float dx = zv.x - ev.x, dy = zv.y - ev.y, dz = zv.z - ev.z, dw = zv.w - ev.w;
        s += dx * dx + dy * dy + dz * dz + dw * dw;
    }
    for (int off = 32; off; off >>= 1) s += __shfl_down(s, off);
    __shared__ float red[4];
    if ((t & 63) == 0) red[t >> 6] = s;
    __syncthreads();
    if (t == 0) part[b] = red[0] + red[1] + red[2] + red[3];
}

__global__ void loss_kernel(const float* __restrict__ part, float* __restrict__ out_loss) {
    const int t = threadIdx.x;
    double s = 0.0;
    for (int i = t; i < 1024; i += 256) s += (double)part[i];
    for (int off = 32; off; off >>= 1) s += __shfl_down(s, off);
    __shared__ double red[4];
    if ((t & 63) == 0) red[t >> 6] = s;
    __syncthreads();
    if (t == 0) {
        const double total = red[0] + red[1] + red[2] + red[3];
        out_loss[0] = (float)(0.25 * (total / (double)((size_t)NROWS * DDIM)));
    }
}

// ================= launch ==================================================
#define EE_OFF   0
#define ZZ_OFF   8192
#define EH_OFF   73728
#define ZH_OFF   (EH_OFF + (size_t)KCODES * DDIM * 2)       // +3145728
#define BMIN_OFF (ZH_OFF + (size_t)NROWS * DDIM * 2)        // +25165824
#define SLOT_OFF (BMIN_OFF + (size_t)NCB2 * NROWS * 4)      // +524288
#define WS_NEED  (SLOT_OFF + (size_t)NCB2 * NROWS * 8 * 8)  // ~35.6 MB
#define PART_OFF 73728                                      // fallback (exclusive)
#define PV_OFF   81920

extern "C" void kernel_launch(void* const* d_in, const int* in_sizes, int n_in,
                              void* d_out, int out_size, void* d_ws, size_t ws_size,
                              hipStream_t stream) {
    const float* z   = (const float*)d_in[0];
    const float* emb = (const float*)d_in[1];

    float* out0     = (float*)d_out;
    float* out_ids  = out0 + (size_t)NROWS * DDIM;
    float* out_loss = out_ids + NROWS;

    char* ws = (char*)d_ws;
    float* ee   = (float*)(ws + EE_OFF);
    float* zzws = (float*)(ws + ZZ_OFF);

    if (ws_size >= WS_NEED) {
        ushort_t* Eh   = (ushort_t*)(ws + EH_OFF);
        ushort_t* Zh   = (ushort_t*)(ws + ZH_OFF);
        float*    bmin = (float*)(ws + BMIN_OFF);
        float2*   slot = (float2*)(ws + SLOT_OFF);
        prep_kernel<<<KCODES + NROWS / 4, 256, 0, stream>>>(z, emb, ee, zzws, Zh, Eh, out_loss);
        mfma_kernel<<<(NROWS / 128) * NCB2, 256, 0, stream>>>(Zh, Eh, ee, bmin, slot);
        combine_select_gather<<<NROWS / 4, 256, 0, stream>>>(bmin, slot, ee, zzws, z, emb,
                                                             out_ids, out0, out_loss);
    } else {
        float* part = (float*)(ws + PART_OFF);
        float* pval = (float*)(ws + PV_OFF);
        int*   pidx = (int*)(ws + PV_OFF + 131072);
        ee_kernel<<<KCODES, 256, 0, stream>>>(emb, ee);
        zz_kernel<<<NROWS / 4, 256, 0, stream>>>(z, zzws);
        argmin_kernel<<<(NROWS / BM) * SPLITC, 256, 0, stream>>>(z, emb, ee, zzws, pval, pidx);
        combine_kernel<<<NROWS / 256, 256, 0, stream>>>(pval, pidx, out_ids);
        gather_kernel<<<NROWS / 16, 256, 0, stream>>>(z, emb, out_ids, out0, part);
        loss_kernel<<<1, 256, 0, stream>>>(part, out_loss);
    }
}